// Round 5
// baseline (434.860 us; speedup 1.0000x reference)
//
#include <hip/hip_runtime.h>
#include <cstdint>
#include <cstddef>

typedef __bf16 bf16;
typedef __bf16 bf16x8 __attribute__((ext_vector_type(8)));
typedef float  f32x4  __attribute__((ext_vector_type(4)));

#define MFMA16(a, b, c) __builtin_amdgcn_mfma_f32_16x16x32_bf16((a), (b), (c), 0, 0, 0)

// async global->LDS, 16B per lane; data lands at wave-uniform base + lane*16
static __device__ __forceinline__ void gld16(const bf16* g, bf16* l) {
    __builtin_amdgcn_global_load_lds(
        (const __attribute__((address_space(1))) void*)g,
        (__attribute__((address_space(3))) void*)l, 16, 0, 0);
}

static __device__ __forceinline__ unsigned pack_bf16x2(bf16 a, bf16 b) {
    union { unsigned u; bf16 h[2]; } t;
    t.h[0] = a; t.h[1] = b;
    return t.u;
}

// ---------------------------------------------------------------------------
// Weight prep: fp32 [K][N] -> bf16 [Nrows][Kpad] (transposed, zero-padded)
// ---------------------------------------------------------------------------
__global__ __launch_bounds__(256) void tcvt_kernel(const float* __restrict__ src,
                                                   bf16* __restrict__ dst,
                                                   int K, int N, int Kpad, int Nrows) {
    __shared__ float t[32][33];
    int k0 = blockIdx.x * 32, n0 = blockIdx.y * 32;
#pragma unroll
    for (int i = threadIdx.y; i < 32; i += 8) {
        int k = k0 + i, n = n0 + threadIdx.x;
        t[i][threadIdx.x] = (k < K && n < N) ? src[(size_t)k * N + n] : 0.f;
    }
    __syncthreads();
#pragma unroll
    for (int i = threadIdx.y; i < 32; i += 8) {
        int n = n0 + i, k = k0 + threadIdx.x;
        if (n < Nrows && k < Kpad) dst[(size_t)n * Kpad + k] = (bf16)t[threadIdx.x][i];
    }
}

// ---------------------------------------------------------------------------
// LayerNorm: one wave per 512-element row, fp32 in, bf16 out
// ---------------------------------------------------------------------------
__global__ __launch_bounds__(256) void ln_kernel(const float* __restrict__ x,
                                                 const float* __restrict__ g,
                                                 const float* __restrict__ b,
                                                 bf16* __restrict__ out) {
    int row  = blockIdx.x * 4 + (threadIdx.x >> 6);
    int lane = threadIdx.x & 63;
    const float* xr = x + (size_t)row * 512 + lane * 8;
    float4 v0 = *(const float4*)xr;
    float4 v1 = *(const float4*)(xr + 4);
    float s  = v0.x + v0.y + v0.z + v0.w + v1.x + v1.y + v1.z + v1.w;
    float ss = v0.x*v0.x + v0.y*v0.y + v0.z*v0.z + v0.w*v0.w
             + v1.x*v1.x + v1.y*v1.y + v1.z*v1.z + v1.w*v1.w;
#pragma unroll
    for (int off = 1; off < 64; off <<= 1) {
        s  += __shfl_xor(s, off, 64);
        ss += __shfl_xor(ss, off, 64);
    }
    float mean = s * (1.0f / 512.0f);
    float var  = ss * (1.0f / 512.0f) - mean * mean;
    float rstd = rsqrtf(var + 1e-5f);
    const float* gr = g + lane * 8;
    const float* br = b + lane * 8;
    float4 g0 = *(const float4*)gr, g1 = *(const float4*)(gr + 4);
    float4 b0 = *(const float4*)br, b1 = *(const float4*)(br + 4);
    bf16x8 o;
    o[0] = (bf16)((v0.x - mean) * rstd * g0.x + b0.x);
    o[1] = (bf16)((v0.y - mean) * rstd * g0.y + b0.y);
    o[2] = (bf16)((v0.z - mean) * rstd * g0.z + b0.z);
    o[3] = (bf16)((v0.w - mean) * rstd * g0.w + b0.w);
    o[4] = (bf16)((v1.x - mean) * rstd * g1.x + b1.x);
    o[5] = (bf16)((v1.y - mean) * rstd * g1.y + b1.y);
    o[6] = (bf16)((v1.z - mean) * rstd * g1.z + b1.z);
    o[7] = (bf16)((v1.w - mean) * rstd * g1.w + b1.w);
    *(uint4*)(out + (size_t)row * 512 + lane * 8) = *(uint4*)&o;
}

// ---------------------------------------------------------------------------
// bf16 GEMM, 256(m) x 128(n) block tile, BK=64: A [M][K], B [N][K] bf16.
// Wave tile 128m x 64n (acc 8x4). 64 MFMA / 24 ds_read_b128 / 12 gld16
// per wave per K-iter (2.67 MFMA:ds_read vs 2.0 at 128x128).
// EPI 0: fused l2norm + qk-scale + xPos rotary epilogue -> q/k/v scatter
// EPI 1: Cf = acc + res            (out-proj + residual)
// EPI 2: Cf = acc + res + bias[n]  (ff2 + bias + residual, in-place on d_out)
// ---------------------------------------------------------------------------
template <int EPI>
__global__ __launch_bounds__(256, 2) void gemm_bt(
    const bf16* __restrict__ A, const bf16* __restrict__ Bm, int K,
    bf16* __restrict__ Cb, float* Cf,
    const float* res, const float* __restrict__ bias) {
    __shared__ __align__(16) bf16 As[256 * 64];
    __shared__ __align__(16) bf16 Bs[128 * 64];
    const int tid  = threadIdx.x;
    const int wid  = tid >> 6;
    const int lane = tid & 63;
    const int quad = lane >> 4;
    const int l16  = lane & 15;
    const int wm   = wid >> 1;
    const int wn   = wid & 1;
    const int m0   = blockIdx.y * 256;
    const int n0   = blockIdx.x * 128;

    f32x4 z4 = {0.f, 0.f, 0.f, 0.f};
    f32x4 acc[8][4];
#pragma unroll
    for (int i = 0; i < 8; ++i)
#pragma unroll
        for (int j = 0; j < 4; ++j) acc[i][j] = z4;

    for (int kt = 0; kt < K; kt += 64) {
        __syncthreads();
#pragma unroll
        for (int p = 0; p < 8; ++p) {          // A: 256 rows x 8 chunks
            int c   = tid + (p << 8);
            int row = c >> 3;
            int g   = (c & 7) ^ (row & 7);
            gld16(A + (size_t)(m0 + row) * K + kt + g * 8, As + c * 8);
        }
#pragma unroll
        for (int p = 0; p < 4; ++p) {          // B: 128 rows x 8 chunks
            int c   = tid + (p << 8);
            int row = c >> 3;
            int g   = (c & 7) ^ (row & 7);
            gld16(Bm + (size_t)(n0 + row) * K + kt + g * 8, Bs + c * 8);
        }
        __syncthreads();
#pragma unroll
        for (int ks = 0; ks < 2; ++ks) {
            bf16x8 af[8], bfr[4];
#pragma unroll
            for (int i = 0; i < 8; ++i) {
                int r = wm * 128 + i * 16 + l16;
                af[i] = *(const bf16x8*)(As + r * 64 + ((((ks << 2) + quad)) ^ (r & 7)) * 8);
            }
#pragma unroll
            for (int j = 0; j < 4; ++j) {
                int r = wn * 64 + j * 16 + l16;
                bfr[j] = *(const bf16x8*)(Bs + r * 64 + ((((ks << 2) + quad)) ^ (r & 7)) * 8);
            }
#pragma unroll
            for (int i = 0; i < 8; ++i)
#pragma unroll
                for (int j = 0; j < 4; ++j)
                    acc[i][j] = MFMA16(af[i], bfr[j], acc[i][j]);
        }
    }

    if (EPI == 0) {
        // Wave-uniform section: n-range [nbase, nbase+64) is head-aligned.
        const int nbase = n0 + wn * 64;
        const int which = nbase >> 9;     // 0=q, 1=k, 2=v
        const int hh    = (nbase >> 6) & 7;
        if (which == 2) {
#pragma unroll
            for (int i = 0; i < 8; ++i)
#pragma unroll
                for (int j = 0; j < 4; ++j)
#pragma unroll
                    for (int r = 0; r < 4; ++r) {
                        int m = m0 + wm * 128 + i * 16 + quad * 4 + r;
                        int d = j * 16 + l16;
                        int bb = m >> 13, nn = m & 8191;
                        Cb[(size_t)2 * 8388608 +
                           ((size_t)(bb * 8 + hh) * 8192 + nn) * 64 + d] =
                            (bf16)acc[i][j][r];
                    }
        } else {
            // l2norm + scale + xPos rotary, all in registers + DPP shuffles.
            const float* scale = (which == 0) ? res : bias;  // qscale / kscale
            const float sgn = (which == 0) ? 1.0f : -1.0f;   // xs vs 1/xs
            float sc[4], revf[4], lg[4];
#pragma unroll
            for (int j = 0; j < 4; ++j) {
                int d  = j * 16 + l16;
                int i2 = d & 31;
                sc[j]   = scale[d];
                // 10000^(-i2/32) / (2*pi)
                revf[j] = __builtin_exp2f(-(float)i2 * 0.4152410118609190f) *
                          0.15915494309189535f;
                lg[j]   = __builtin_log2f(((float)(2 * i2) + 25.6f) * (1.0f / 89.6f));
            }
            const size_t obase = (size_t)which * 8388608;
#pragma unroll
            for (int i = 0; i < 8; ++i)
#pragma unroll
                for (int r = 0; r < 4; ++r) {
                    int m = m0 + wm * 128 + i * 16 + quad * 4 + r;
                    int bb = m >> 13, nn = m & 8191;
                    float ss = 0.f;
#pragma unroll
                    for (int j = 0; j < 4; ++j) ss += acc[i][j][r] * acc[i][j][r];
                    ss += __shfl_xor(ss, 1, 64);
                    ss += __shfl_xor(ss, 2, 64);
                    ss += __shfl_xor(ss, 4, 64);
                    ss += __shfl_xor(ss, 8, 64);
                    float rn = rsqrtf(fmaxf(ss, 1e-24f));
                    float val[4];
#pragma unroll
                    for (int j = 0; j < 4; ++j) val[j] = acc[i][j][r] * rn * sc[j];
                    float fn = (float)nn;
                    float pw = (fn - 4096.0f) * (1.0f / 256.0f) * sgn;
#pragma unroll
                    for (int j = 0; j < 4; ++j) {
                        float xrev = fn * revf[j];
                        xrev -= floorf(xrev);
                        float cv = __builtin_amdgcn_cosf(xrev);
                        float sv = __builtin_amdgcn_sinf(xrev);
                        float xs = __builtin_exp2f(pw * lg[j]);
                        float rh = (j < 2) ? -val[j ^ 2] : val[j ^ 2];
                        float ov = (val[j] * cv + rh * sv) * xs;
                        int d = j * 16 + l16;
                        Cb[obase + ((size_t)(bb * 8 + hh) * 8192 + nn) * 64 + d] =
                            (bf16)ov;
                    }
                }
        }
    } else {
#pragma unroll
        for (int i = 0; i < 8; ++i)
#pragma unroll
            for (int j = 0; j < 4; ++j)
#pragma unroll
                for (int r = 0; r < 4; ++r) {
                    int m = m0 + wm * 128 + i * 16 + quad * 4 + r;
                    int n = n0 + wn * 64 + j * 16 + l16;
                    float v = acc[i][j][r];
                    size_t idx = (size_t)m * 512 + n;
                    if (EPI == 1) {
                        Cf[idx] = v + res[idx];
                    } else {
                        float rv = res[idx];
                        Cf[idx] = v + rv + bias[n];
                    }
                }
    }
}

// ---------------------------------------------------------------------------
// Local windowed attention, fixed-max softmax (|s| <= 8 by construction).
// Block = 128 q-rows, wave = 32 rows (2 m-tiles). K/V chunks of 128 in LDS.
// ---------------------------------------------------------------------------
__global__ __launch_bounds__(256) void attn_kernel(const bf16* __restrict__ q,
                                                   const bf16* __restrict__ k,
                                                   const bf16* __restrict__ v,
                                                   bf16* __restrict__ o) {
    __shared__ __align__(16) bf16 Ks[128 * 64];
    __shared__ __align__(16) bf16 Vt[64][136];
    __shared__ __align__(16) bf16 Ps[4][16][136];
    const int tid  = threadIdx.x;
    const int wid  = tid >> 6;
    const int lane = tid & 63;
    const int quad = lane >> 4;
    const int l16  = lane & 15;
    const int lid = (blockIdx.x & 7) * 128 + (blockIdx.x >> 3);
    const int bh  = lid >> 6;
    const int q0  = (lid & 63) * 128;
    const size_t base = (size_t)bh * 8192;

    bf16x8 aq[2][2];
#pragma unroll
    for (int mt = 0; mt < 2; ++mt) {
        int qrow = q0 + wid * 32 + mt * 16 + l16;
        const bf16* qp = q + (base + qrow) * 64 + quad * 8;
        aq[mt][0] = *(const bf16x8*)qp;
        aq[mt][1] = *(const bf16x8*)(qp + 32);
    }
    f32x4 z4 = {0.f, 0.f, 0.f, 0.f};
    f32x4 accO[2][4];
    float rs[2][4];
#pragma unroll
    for (int mt = 0; mt < 2; ++mt)
#pragma unroll
        for (int j = 0; j < 4; ++j) { accO[mt][j] = z4; rs[mt][j] = 0.f; }

    int klo = q0 - 512;
    if (klo < 0) klo = 0;
    for (int kc = klo; kc < q0 + 128; kc += 128) {
        __syncthreads();
#pragma unroll
        for (int p = 0; p < 4; ++p) {
            int c   = tid + (p << 8);
            int row = c >> 3;
            int g   = (c & 7) ^ (row & 7);
            gld16(k + (base + kc + row) * 64 + g * 8, Ks + c * 8);
        }
        {
            int kp = lane;
#pragma unroll
            for (int w2 = 0; w2 < 2; ++w2) {
                int dc = wid * 2 + w2;
                const bf16* vp = v + (base + kc + kp * 2) * 64 + dc * 8;
                union { uint4 u; bf16 h[8]; } va, vb2;
                va.u  = *(const uint4*)vp;
                vb2.u = *(const uint4*)(vp + 64);
#pragma unroll
                for (int j = 0; j < 8; ++j)
                    *(unsigned*)&Vt[dc * 8 + j][kp * 2] =
                        pack_bf16x2(va.h[j], vb2.h[j]);
            }
        }
        __syncthreads();
#pragma unroll
        for (int mt = 0; mt < 2; ++mt) {
            f32x4 s[8];
#pragma unroll
            for (int ns = 0; ns < 8; ++ns) {
                int row = ns * 16 + l16;
                bf16x8 b0 = *(const bf16x8*)(Ks + row * 64 + ((quad    ) ^ (row & 7)) * 8);
                bf16x8 b1 = *(const bf16x8*)(Ks + row * 64 + ((4 + quad) ^ (row & 7)) * 8);
                f32x4 t = z4;
                t = MFMA16(aq[mt][0], b0, t);
                t = MFMA16(aq[mt][1], b1, t);
                s[ns] = t;
            }
            int gi0 = q0 + wid * 32 + mt * 16 + quad * 4;
#pragma unroll
            for (int ns = 0; ns < 8; ++ns) {
                int gj = kc + ns * 16 + l16;
#pragma unroll
                for (int r = 0; r < 4; ++r) {
                    int e = gi0 + r - gj;  // valid iff 0 <= e <= 512
                    float p = __builtin_exp2f(
                        fmaf(s[ns][r], 11.541560327f, -11.541560327f));
                    p = ((unsigned)e <= 512u) ? p : 0.f;
                    rs[mt][r] += p;
                    Ps[wid][quad * 4 + r][ns * 16 + l16] = (bf16)p;
                }
            }
#pragma unroll
            for (int ks2 = 0; ks2 < 4; ++ks2) {
                bf16x8 ap = *(const bf16x8*)&Ps[wid][l16][ks2 * 32 + quad * 8];
#pragma unroll
                for (int ds = 0; ds < 4; ++ds) {
                    bf16x8 bv = *(const bf16x8*)&Vt[ds * 16 + l16][ks2 * 32 + quad * 8];
                    accO[mt][ds] = MFMA16(ap, bv, accO[mt][ds]);
                }
            }
        }
    }
#pragma unroll
    for (int mt = 0; mt < 2; ++mt)
#pragma unroll
        for (int r = 0; r < 4; ++r) {
            float t = rs[mt][r];
            t += __shfl_xor(t, 1, 64);
            t += __shfl_xor(t, 2, 64);
            t += __shfl_xor(t, 4, 64);
            t += __shfl_xor(t, 8, 64);
            rs[mt][r] = 1.0f / t;
        }
    int bb = bh >> 3, hh = bh & 7;
#pragma unroll
    for (int mt = 0; mt < 2; ++mt)
#pragma unroll
        for (int ds = 0; ds < 4; ++ds)
#pragma unroll
            for (int r = 0; r < 4; ++r) {
                int m = q0 + wid * 32 + mt * 16 + quad * 4 + r;
                o[((size_t)(bb * 8192 + m)) * 512 + hh * 64 + ds * 16 + l16] =
                    (bf16)(accO[mt][ds][r] * rs[mt][r]);
            }
}

// ---------------------------------------------------------------------------
// FF1: fused dual-half (a + gate) GEMM + exact GELU -> act [16384][1408] bf16.
// 256(m) x 64(n per half) block tile; wave tile 128m x 32n per half.
// ---------------------------------------------------------------------------
__global__ __launch_bounds__(256, 2) void ff1_kernel(const bf16* __restrict__ A,
                                                     const bf16* __restrict__ W1T,
                                                     const float* __restrict__ b1,
                                                     bf16* __restrict__ act) {
    __shared__ __align__(16) bf16 As[256 * 64];
    __shared__ __align__(16) bf16 Bsa[64 * 64];
    __shared__ __align__(16) bf16 Bsg[64 * 64];
    const int tid  = threadIdx.x;
    const int wid  = tid >> 6;
    const int lane = tid & 63;
    const int quad = lane >> 4;
    const int l16  = lane & 15;
    const int wm   = wid >> 1;
    const int wn   = wid & 1;
    const int m0   = blockIdx.y * 256;
    const int n0   = blockIdx.x * 64;

    f32x4 z4 = {0.f, 0.f, 0.f, 0.f};
    f32x4 aa[8][2], ag[8][2];
#pragma unroll
    for (int i = 0; i < 8; ++i)
#pragma unroll
        for (int j = 0; j < 2; ++j) { aa[i][j] = z4; ag[i][j] = z4; }

    for (int kt = 0; kt < 512; kt += 64) {
        __syncthreads();
#pragma unroll
        for (int p = 0; p < 8; ++p) {
            int c   = tid + (p << 8);
            int row = c >> 3;
            int g   = (c & 7) ^ (row & 7);
            gld16(A + (size_t)(m0 + row) * 512 + kt + g * 8, As + c * 8);
        }
#pragma unroll
        for (int p = 0; p < 2; ++p) {
            int c   = tid + (p << 8);
            int row = c >> 3;
            int g   = (c & 7) ^ (row & 7);
            gld16(W1T + (size_t)(n0 + row) * 512 + kt + g * 8, Bsa + c * 8);
            gld16(W1T + (size_t)(1365 + n0 + row) * 512 + kt + g * 8, Bsg + c * 8);
        }
        __syncthreads();
#pragma unroll
        for (int ks = 0; ks < 2; ++ks) {
            bf16x8 af[8];
#pragma unroll
            for (int i = 0; i < 8; ++i) {
                int r = wm * 128 + i * 16 + l16;
                af[i] = *(const bf16x8*)(As + r * 64 + ((((ks << 2) + quad)) ^ (r & 7)) * 8);
            }
#pragma unroll
            for (int j = 0; j < 2; ++j) {
                int r = wn * 32 + j * 16 + l16;
                int sl = (((ks << 2) + quad)) ^ (r & 7);
                bf16x8 ba = *(const bf16x8*)(Bsa + r * 64 + sl * 8);
                bf16x8 bg = *(const bf16x8*)(Bsg + r * 64 + sl * 8);
#pragma unroll
                for (int i = 0; i < 8; ++i) {
                    aa[i][j] = MFMA16(af[i], ba, aa[i][j]);
                    ag[i][j] = MFMA16(af[i], bg, ag[i][j]);
                }
            }
        }
    }

#pragma unroll
    for (int i = 0; i < 8; ++i)
#pragma unroll
        for (int j = 0; j < 2; ++j)
#pragma unroll
            for (int r = 0; r < 4; ++r) {
                int m  = m0 + wm * 128 + i * 16 + quad * 4 + r;
                int n  = n0 + wn * 32 + j * 16 + l16;
                bf16 outv = (bf16)0.f;
                if (n < 1365) {
                    float av = aa[i][j][r] + b1[n];
                    float gv = ag[i][j][r] + b1[1365 + n];
                    float gel = 0.5f * gv * (1.0f + erff(gv * 0.70710678118f));
                    outv = (bf16)(av * gel);
                }
                act[(size_t)m * 1408 + n] = outv;
            }
}

// ---------------------------------------------------------------------------
// Launch
// ---------------------------------------------------------------------------
extern "C" void kernel_launch(void* const* d_in, const int* in_sizes, int n_in,
                              void* d_out, int out_size, void* d_ws, size_t ws_size,
                              hipStream_t stream) {
    const float* x      = (const float*)d_in[0];
    const float* ln1g   = (const float*)d_in[1];
    const float* ln1b   = (const float*)d_in[2];
    const float* Wqkv   = (const float*)d_in[3];
    const float* qscale = (const float*)d_in[4];
    const float* kscale = (const float*)d_in[5];
    const float* Wout   = (const float*)d_in[6];
    const float* ln2g   = (const float*)d_in[7];
    const float* ln2b   = (const float*)d_in[8];
    const float* W1     = (const float*)d_in[9];
    const float* b1     = (const float*)d_in[10];
    const float* W2     = (const float*)d_in[11];
    const float* b2     = (const float*)d_in[12];
    float* out = (float*)d_out;

    char* ws = (char*)d_ws;
    const size_t MB = 1024 * 1024;
    bf16* h   = (bf16*)(ws);             // 16 MB (reused: attn out o, then h2)
    bf16* qb  = (bf16*)(ws + 16 * MB);   // q/k/v contiguous 16..64 MB
    bf16* kb  = (bf16*)(ws + 32 * MB);
    bf16* vb  = (bf16*)(ws + 48 * MB);
    bf16* wts = (bf16*)(ws + 64 * MB);   // bf16 transposed weights, ~6.2 MB
    bf16* WqkvT = wts;                   // [1536][512]
    bf16* WoutT = WqkvT + 1536 * 512;    // [512][512]
    bf16* W1T   = WoutT + 512 * 512;     // [2816][512] (rows >=2730 zero)
    bf16* W2T   = W1T + 2816 * 512;      // [512][1408] (cols >=1365 zero)
    bf16* ob  = h;
    bf16* h2  = h;
    bf16* act = qb;                      // 46.2 MB over dead q/k/v
    float* x1 = out;                     // pre-FF residual lives in d_out

    // 0. weight prep (fp32 [K][N] -> bf16 [N][Kpad])
    tcvt_kernel<<<dim3(16, 48), dim3(32, 8), 0, stream>>>(Wqkv, WqkvT, 512, 1536, 512, 1536);
    tcvt_kernel<<<dim3(16, 16), dim3(32, 8), 0, stream>>>(Wout, WoutT, 512, 512, 512, 512);
    tcvt_kernel<<<dim3(16, 88), dim3(32, 8), 0, stream>>>(W1, W1T, 512, 2730, 512, 2816);
    tcvt_kernel<<<dim3(44, 16), dim3(32, 8), 0, stream>>>(W2, W2T, 1365, 512, 1408, 512);
    // 1. LN1
    ln_kernel<<<4096, 256, 0, stream>>>(x, ln1g, ln1b, h);
    // 2. QKV GEMM with fused l2norm+scale+rotary epilogue -> per-head q/k/v
    gemm_bt<0><<<dim3(12, 64), 256, 0, stream>>>(h, WqkvT, 512, qb, nullptr,
                                                 qscale, kscale);
    // 3. local attention (128-row q-tiles, XCD-swizzled flat grid)
    attn_kernel<<<1024, 256, 0, stream>>>(qb, kb, vb, ob);
    // 4. out-proj + residual -> x1 (d_out, fp32)
    gemm_bt<1><<<dim3(4, 64), 256, 0, stream>>>(ob, WoutT, 512, nullptr, x1, x, nullptr);
    // 5. LN2 (reads d_out)
    ln_kernel<<<4096, 256, 0, stream>>>(x1, ln2g, ln2b, h2);
    // 6. FF1 fused dual-half + exact gelu -> act
    ff1_kernel<<<dim3(22, 64), 256, 0, stream>>>(h2, W1T, b1, act);
    // 7. FF2 + b2 + residual (in-place on d_out)
    gemm_bt<2><<<dim3(4, 64), 256, 0, stream>>>(act, W2T, 1408, nullptr, out, x1, b2);
}

// Round 6
// 387.077 us; speedup vs baseline: 1.1234x; 1.1234x over previous
//
#include <hip/hip_runtime.h>
#include <cstdint>
#include <cstddef>

typedef __bf16 bf16;
typedef __bf16 bf16x8 __attribute__((ext_vector_type(8)));
typedef float  f32x4  __attribute__((ext_vector_type(4)));

#define MFMA16(a, b, c) __builtin_amdgcn_mfma_f32_16x16x32_bf16((a), (b), (c), 0, 0, 0)

// async global->LDS, 16B per lane; data lands at wave-uniform base + lane*16
static __device__ __forceinline__ void gld16(const bf16* g, bf16* l) {
    __builtin_amdgcn_global_load_lds(
        (const __attribute__((address_space(1))) void*)g,
        (__attribute__((address_space(3))) void*)l, 16, 0, 0);
}

static __device__ __forceinline__ unsigned pack_bf16x2(bf16 a, bf16 b) {
    union { unsigned u; bf16 h[2]; } t;
    t.h[0] = a; t.h[1] = b;
    return t.u;
}

// ---------------------------------------------------------------------------
// Merged prep: LN1 (blocks 0..4095) + 4 weight transposes/converts
// (fp32 [K][N] -> bf16 [Nrows][Kpad], zero-padded) in one dispatch.
// ---------------------------------------------------------------------------
static __device__ __forceinline__ void tcvt_block(const float* __restrict__ src,
                                                  bf16* __restrict__ dst,
                                                  int K, int N, int Kpad, int Nrows,
                                                  int bkx, int bny, int tid,
                                                  float (*t)[33]) {
    int tx = tid & 31, ty = tid >> 5;
    int k0 = bkx * 32, n0 = bny * 32;
#pragma unroll
    for (int i = ty; i < 32; i += 8) {
        int k = k0 + i, n = n0 + tx;
        t[i][tx] = (k < K && n < N) ? src[(size_t)k * N + n] : 0.f;
    }
    __syncthreads();
#pragma unroll
    for (int i = ty; i < 32; i += 8) {
        int n = n0 + i, k = k0 + tx;
        if (n < Nrows && k < Kpad) dst[(size_t)n * Kpad + k] = (bf16)t[tx][i];
    }
}

__global__ __launch_bounds__(256) void prep_kernel(
    const float* __restrict__ x, const float* __restrict__ g,
    const float* __restrict__ b, bf16* __restrict__ h,
    const float* __restrict__ Wqkv, bf16* __restrict__ WqkvT,
    const float* __restrict__ Wout, bf16* __restrict__ WoutT,
    const float* __restrict__ W1, bf16* __restrict__ W1T,
    const float* __restrict__ W2, bf16* __restrict__ W2T) {
    __shared__ float t[32][33];
    const int bid = blockIdx.x;
    const int tid = threadIdx.x;
    if (bid < 4096) {
        // LayerNorm: one wave per 512-element row
        int row  = bid * 4 + (tid >> 6);
        int lane = tid & 63;
        const float* xr = x + (size_t)row * 512 + lane * 8;
        float4 v0 = *(const float4*)xr;
        float4 v1 = *(const float4*)(xr + 4);
        float s  = v0.x + v0.y + v0.z + v0.w + v1.x + v1.y + v1.z + v1.w;
        float ss = v0.x*v0.x + v0.y*v0.y + v0.z*v0.z + v0.w*v0.w
                 + v1.x*v1.x + v1.y*v1.y + v1.z*v1.z + v1.w*v1.w;
#pragma unroll
        for (int off = 1; off < 64; off <<= 1) {
            s  += __shfl_xor(s, off, 64);
            ss += __shfl_xor(ss, off, 64);
        }
        float mean = s * (1.0f / 512.0f);
        float var  = ss * (1.0f / 512.0f) - mean * mean;
        float rstd = rsqrtf(var + 1e-5f);
        const float* gr = g + lane * 8;
        const float* br = b + lane * 8;
        float4 g0 = *(const float4*)gr, g1 = *(const float4*)(gr + 4);
        float4 b0 = *(const float4*)br, b1 = *(const float4*)(br + 4);
        bf16x8 o;
        o[0] = (bf16)((v0.x - mean) * rstd * g0.x + b0.x);
        o[1] = (bf16)((v0.y - mean) * rstd * g0.y + b0.y);
        o[2] = (bf16)((v0.z - mean) * rstd * g0.z + b0.z);
        o[3] = (bf16)((v0.w - mean) * rstd * g0.w + b0.w);
        o[4] = (bf16)((v1.x - mean) * rstd * g1.x + b1.x);
        o[5] = (bf16)((v1.y - mean) * rstd * g1.y + b1.y);
        o[6] = (bf16)((v1.z - mean) * rstd * g1.z + b1.z);
        o[7] = (bf16)((v1.w - mean) * rstd * g1.w + b1.w);
        *(uint4*)(h + (size_t)row * 512 + lane * 8) = *(uint4*)&o;
    } else if (bid < 4096 + 768) {          // Wqkv: 16 x 48
        int bb = bid - 4096;
        tcvt_block(Wqkv, WqkvT, 512, 1536, 512, 1536, bb & 15, bb >> 4, tid, t);
    } else if (bid < 4096 + 768 + 256) {    // Wout: 16 x 16
        int bb = bid - (4096 + 768);
        tcvt_block(Wout, WoutT, 512, 512, 512, 512, bb & 15, bb >> 4, tid, t);
    } else if (bid < 4096 + 768 + 256 + 1408) {  // W1: 16 x 88
        int bb = bid - (4096 + 768 + 256);
        tcvt_block(W1, W1T, 512, 2730, 512, 2816, bb & 15, bb >> 4, tid, t);
    } else {                                 // W2: 44 x 16
        int bb = bid - (4096 + 768 + 256 + 1408);
        tcvt_block(W2, W2T, 1365, 512, 1408, 512, bb % 44, bb / 44, tid, t);
    }
}

// ---------------------------------------------------------------------------
// LayerNorm (standalone, for LN2): one wave per 512-element row
// ---------------------------------------------------------------------------
__global__ __launch_bounds__(256) void ln_kernel(const float* __restrict__ x,
                                                 const float* __restrict__ g,
                                                 const float* __restrict__ b,
                                                 bf16* __restrict__ out) {
    int row  = blockIdx.x * 4 + (threadIdx.x >> 6);
    int lane = threadIdx.x & 63;
    const float* xr = x + (size_t)row * 512 + lane * 8;
    float4 v0 = *(const float4*)xr;
    float4 v1 = *(const float4*)(xr + 4);
    float s  = v0.x + v0.y + v0.z + v0.w + v1.x + v1.y + v1.z + v1.w;
    float ss = v0.x*v0.x + v0.y*v0.y + v0.z*v0.z + v0.w*v0.w
             + v1.x*v1.x + v1.y*v1.y + v1.z*v1.z + v1.w*v1.w;
#pragma unroll
    for (int off = 1; off < 64; off <<= 1) {
        s  += __shfl_xor(s, off, 64);
        ss += __shfl_xor(ss, off, 64);
    }
    float mean = s * (1.0f / 512.0f);
    float var  = ss * (1.0f / 512.0f) - mean * mean;
    float rstd = rsqrtf(var + 1e-5f);
    const float* gr = g + lane * 8;
    const float* br = b + lane * 8;
    float4 g0 = *(const float4*)gr, g1 = *(const float4*)(gr + 4);
    float4 b0 = *(const float4*)br, b1 = *(const float4*)(br + 4);
    bf16x8 o;
    o[0] = (bf16)((v0.x - mean) * rstd * g0.x + b0.x);
    o[1] = (bf16)((v0.y - mean) * rstd * g0.y + b0.y);
    o[2] = (bf16)((v0.z - mean) * rstd * g0.z + b0.z);
    o[3] = (bf16)((v0.w - mean) * rstd * g0.w + b0.w);
    o[4] = (bf16)((v1.x - mean) * rstd * g1.x + b1.x);
    o[5] = (bf16)((v1.y - mean) * rstd * g1.y + b1.y);
    o[6] = (bf16)((v1.z - mean) * rstd * g1.z + b1.z);
    o[7] = (bf16)((v1.w - mean) * rstd * g1.w + b1.w);
    *(uint4*)(out + (size_t)row * 512 + lane * 8) = *(uint4*)&o;
}

// ---------------------------------------------------------------------------
// m97-style bf16 GEMM, 128x128 tile (measured sweet spot): A [M][K], B [N][K].
// EPI 0: fused l2norm + qk-scale + xPos rotary epilogue -> q/k/v scatter
// EPI 1: Cf = acc + res            (out-proj + residual)
// EPI 2: Cf = acc + res + bias[n]  (ff2 + bias + residual, in-place on d_out)
// ---------------------------------------------------------------------------
template <int EPI>
__global__ __launch_bounds__(256) void gemm_bt(
    const bf16* __restrict__ A, const bf16* __restrict__ Bm, int K,
    bf16* __restrict__ Cb, float* Cf,
    const float* res, const float* __restrict__ bias) {
    __shared__ __align__(16) bf16 As[128 * 64];
    __shared__ __align__(16) bf16 Bs[128 * 64];
    const int tid  = threadIdx.x;
    const int wid  = tid >> 6;
    const int lane = tid & 63;
    const int quad = lane >> 4;
    const int l16  = lane & 15;
    const int wm   = wid >> 1;
    const int wn   = wid & 1;
    const int m0   = blockIdx.y * 128;
    const int n0   = blockIdx.x * 128;

    f32x4 z4 = {0.f, 0.f, 0.f, 0.f};
    f32x4 acc[4][4];
#pragma unroll
    for (int i = 0; i < 4; ++i)
#pragma unroll
        for (int j = 0; j < 4; ++j) acc[i][j] = z4;

    for (int kt = 0; kt < K; kt += 64) {
        __syncthreads();
#pragma unroll
        for (int p = 0; p < 4; ++p) {
            int c   = tid + (p << 8);
            int row = c >> 3;
            int g   = (c & 7) ^ (row & 7);
            gld16(A  + (size_t)(m0 + row) * K + kt + g * 8, As + c * 8);
            gld16(Bm + (size_t)(n0 + row) * K + kt + g * 8, Bs + c * 8);
        }
        __syncthreads();
#pragma unroll
        for (int ks = 0; ks < 2; ++ks) {
            bf16x8 af[4], bfr[4];
#pragma unroll
            for (int i = 0; i < 4; ++i) {
                int r = wm * 64 + i * 16 + l16;
                af[i] = *(const bf16x8*)(As + r * 64 + ((((ks << 2) + quad)) ^ (r & 7)) * 8);
            }
#pragma unroll
            for (int j = 0; j < 4; ++j) {
                int r = wn * 64 + j * 16 + l16;
                bfr[j] = *(const bf16x8*)(Bs + r * 64 + ((((ks << 2) + quad)) ^ (r & 7)) * 8);
            }
#pragma unroll
            for (int i = 0; i < 4; ++i)
#pragma unroll
                for (int j = 0; j < 4; ++j)
                    acc[i][j] = MFMA16(af[i], bfr[j], acc[i][j]);
        }
    }

    if (EPI == 0) {
        // Wave-uniform: n-range [nbase, nbase+64) is head-aligned.
        const int nbase = n0 + wn * 64;
        const int which = nbase >> 9;     // 0=q, 1=k, 2=v
        const int hh    = (nbase >> 6) & 7;
        if (which == 2) {
#pragma unroll
            for (int i = 0; i < 4; ++i)
#pragma unroll
                for (int j = 0; j < 4; ++j)
#pragma unroll
                    for (int r = 0; r < 4; ++r) {
                        int m = m0 + wm * 64 + i * 16 + quad * 4 + r;
                        int d = j * 16 + l16;
                        int bb = m >> 13, nn = m & 8191;
                        Cb[(size_t)2 * 8388608 +
                           ((size_t)(bb * 8 + hh) * 8192 + nn) * 64 + d] =
                            (bf16)acc[i][j][r];
                    }
        } else {
            // l2norm + scale + xPos rotary, registers + DPP shuffles only.
            const float* scale = (which == 0) ? res : bias;  // qscale / kscale
            const float sgn = (which == 0) ? 1.0f : -1.0f;   // xs vs 1/xs
            float sc[4], revf[4], lg[4];
#pragma unroll
            for (int j = 0; j < 4; ++j) {
                int d  = j * 16 + l16;
                int i2 = d & 31;
                sc[j]   = scale[d];
                // 10000^(-i2/32) / (2*pi)
                revf[j] = __builtin_exp2f(-(float)i2 * 0.4152410118609190f) *
                          0.15915494309189535f;
                lg[j]   = __builtin_log2f(((float)(2 * i2) + 25.6f) * (1.0f / 89.6f));
            }
            const size_t obase = (size_t)which * 8388608;
#pragma unroll
            for (int i = 0; i < 4; ++i)
#pragma unroll
                for (int r = 0; r < 4; ++r) {
                    int m = m0 + wm * 64 + i * 16 + quad * 4 + r;
                    int bb = m >> 13, nn = m & 8191;
                    float ss = 0.f;
#pragma unroll
                    for (int j = 0; j < 4; ++j) ss += acc[i][j][r] * acc[i][j][r];
                    ss += __shfl_xor(ss, 1, 64);
                    ss += __shfl_xor(ss, 2, 64);
                    ss += __shfl_xor(ss, 4, 64);
                    ss += __shfl_xor(ss, 8, 64);
                    float rn = rsqrtf(fmaxf(ss, 1e-24f));
                    float val[4];
#pragma unroll
                    for (int j = 0; j < 4; ++j) val[j] = acc[i][j][r] * rn * sc[j];
                    float fn = (float)nn;
                    float pw = (fn - 4096.0f) * (1.0f / 256.0f) * sgn;
#pragma unroll
                    for (int j = 0; j < 4; ++j) {
                        float xrev = fn * revf[j];
                        xrev -= floorf(xrev);
                        float cv = __builtin_amdgcn_cosf(xrev);
                        float sv = __builtin_amdgcn_sinf(xrev);
                        float xs = __builtin_exp2f(pw * lg[j]);
                        float rh = (j < 2) ? -val[j ^ 2] : val[j ^ 2];
                        float ov = (val[j] * cv + rh * sv) * xs;
                        int d = j * 16 + l16;
                        Cb[obase + ((size_t)(bb * 8 + hh) * 8192 + nn) * 64 + d] =
                            (bf16)ov;
                    }
                }
        }
    } else {
#pragma unroll
        for (int i = 0; i < 4; ++i)
#pragma unroll
            for (int j = 0; j < 4; ++j)
#pragma unroll
                for (int r = 0; r < 4; ++r) {
                    int m = m0 + wm * 64 + i * 16 + quad * 4 + r;
                    int n = n0 + wn * 64 + j * 16 + l16;
                    float v = acc[i][j][r];
                    size_t idx = (size_t)m * 512 + n;
                    if (EPI == 1) {
                        Cf[idx] = v + res[idx];
                    } else {
                        float rv = res[idx];
                        Cf[idx] = v + rv + bias[n];
                    }
                }
    }
}

// ---------------------------------------------------------------------------
// Local windowed attention, fixed-max softmax (|s| <= 8 by construction).
// Block = 128 q-rows, wave = 32 rows (2 m-tiles). K/V chunks of 128 in LDS.
// ---------------------------------------------------------------------------
__global__ __launch_bounds__(256) void attn_kernel(const bf16* __restrict__ q,
                                                   const bf16* __restrict__ k,
                                                   const bf16* __restrict__ v,
                                                   bf16* __restrict__ o) {
    __shared__ __align__(16) bf16 Ks[128 * 64];
    __shared__ __align__(16) bf16 Vt[64][136];
    __shared__ __align__(16) bf16 Ps[4][16][136];
    const int tid  = threadIdx.x;
    const int wid  = tid >> 6;
    const int lane = tid & 63;
    const int quad = lane >> 4;
    const int l16  = lane & 15;
    const int lid = (blockIdx.x & 7) * 128 + (blockIdx.x >> 3);
    const int bh  = lid >> 6;
    const int q0  = (lid & 63) * 128;
    const size_t base = (size_t)bh * 8192;

    bf16x8 aq[2][2];
#pragma unroll
    for (int mt = 0; mt < 2; ++mt) {
        int qrow = q0 + wid * 32 + mt * 16 + l16;
        const bf16* qp = q + (base + qrow) * 64 + quad * 8;
        aq[mt][0] = *(const bf16x8*)qp;
        aq[mt][1] = *(const bf16x8*)(qp + 32);
    }
    f32x4 z4 = {0.f, 0.f, 0.f, 0.f};
    f32x4 accO[2][4];
    float rs[2][4];
#pragma unroll
    for (int mt = 0; mt < 2; ++mt)
#pragma unroll
        for (int j = 0; j < 4; ++j) { accO[mt][j] = z4; rs[mt][j] = 0.f; }

    int klo = q0 - 512;
    if (klo < 0) klo = 0;
    for (int kc = klo; kc < q0 + 128; kc += 128) {
        __syncthreads();
#pragma unroll
        for (int p = 0; p < 4; ++p) {
            int c   = tid + (p << 8);
            int row = c >> 3;
            int g   = (c & 7) ^ (row & 7);
            gld16(k + (base + kc + row) * 64 + g * 8, Ks + c * 8);
        }
        {
            int kp = lane;
#pragma unroll
            for (int w2 = 0; w2 < 2; ++w2) {
                int dc = wid * 2 + w2;
                const bf16* vp = v + (base + kc + kp * 2) * 64 + dc * 8;
                union { uint4 u; bf16 h[8]; } va, vb2;
                va.u  = *(const uint4*)vp;
                vb2.u = *(const uint4*)(vp + 64);
#pragma unroll
                for (int j = 0; j < 8; ++j)
                    *(unsigned*)&Vt[dc * 8 + j][kp * 2] =
                        pack_bf16x2(va.h[j], vb2.h[j]);
            }
        }
        __syncthreads();
#pragma unroll
        for (int mt = 0; mt < 2; ++mt) {
            f32x4 s[8];
#pragma unroll
            for (int ns = 0; ns < 8; ++ns) {
                int row = ns * 16 + l16;
                bf16x8 b0 = *(const bf16x8*)(Ks + row * 64 + ((quad    ) ^ (row & 7)) * 8);
                bf16x8 b1 = *(const bf16x8*)(Ks + row * 64 + ((4 + quad) ^ (row & 7)) * 8);
                f32x4 t = z4;
                t = MFMA16(aq[mt][0], b0, t);
                t = MFMA16(aq[mt][1], b1, t);
                s[ns] = t;
            }
            int gi0 = q0 + wid * 32 + mt * 16 + quad * 4;
#pragma unroll
            for (int ns = 0; ns < 8; ++ns) {
                int gj = kc + ns * 16 + l16;
#pragma unroll
                for (int r = 0; r < 4; ++r) {
                    int e = gi0 + r - gj;  // valid iff 0 <= e <= 512
                    float p = __builtin_exp2f(
                        fmaf(s[ns][r], 11.541560327f, -11.541560327f));
                    p = ((unsigned)e <= 512u) ? p : 0.f;
                    rs[mt][r] += p;
                    Ps[wid][quad * 4 + r][ns * 16 + l16] = (bf16)p;
                }
            }
#pragma unroll
            for (int ks2 = 0; ks2 < 4; ++ks2) {
                bf16x8 ap = *(const bf16x8*)&Ps[wid][l16][ks2 * 32 + quad * 8];
#pragma unroll
                for (int ds = 0; ds < 4; ++ds) {
                    bf16x8 bv = *(const bf16x8*)&Vt[ds * 16 + l16][ks2 * 32 + quad * 8];
                    accO[mt][ds] = MFMA16(ap, bv, accO[mt][ds]);
                }
            }
        }
    }
#pragma unroll
    for (int mt = 0; mt < 2; ++mt)
#pragma unroll
        for (int r = 0; r < 4; ++r) {
            float t = rs[mt][r];
            t += __shfl_xor(t, 1, 64);
            t += __shfl_xor(t, 2, 64);
            t += __shfl_xor(t, 4, 64);
            t += __shfl_xor(t, 8, 64);
            rs[mt][r] = 1.0f / t;
        }
    int bb = bh >> 3, hh = bh & 7;
#pragma unroll
    for (int mt = 0; mt < 2; ++mt)
#pragma unroll
        for (int ds = 0; ds < 4; ++ds)
#pragma unroll
            for (int r = 0; r < 4; ++r) {
                int m = q0 + wid * 32 + mt * 16 + quad * 4 + r;
                o[((size_t)(bb * 8192 + m)) * 512 + hh * 64 + ds * 16 + l16] =
                    (bf16)(accO[mt][ds][r] * rs[mt][r]);
            }
}

// ---------------------------------------------------------------------------
// FF1: fused dual-half (a + gate) GEMM + exact GELU -> act [16384][1408] bf16.
// 128(m) x 64(n per half) block tile (R4 config — measured best).
// ---------------------------------------------------------------------------
__global__ __launch_bounds__(256) void ff1_kernel(const bf16* __restrict__ A,
                                                  const bf16* __restrict__ W1T,
                                                  const float* __restrict__ b1,
                                                  bf16* __restrict__ act) {
    __shared__ __align__(16) bf16 As[128 * 64];
    __shared__ __align__(16) bf16 Bsa[64 * 64];
    __shared__ __align__(16) bf16 Bsg[64 * 64];
    const int tid  = threadIdx.x;
    const int wid  = tid >> 6;
    const int lane = tid & 63;
    const int quad = lane >> 4;
    const int l16  = lane & 15;
    const int wm   = wid >> 1;
    const int wn   = wid & 1;
    const int m0   = blockIdx.y * 128;
    const int n0   = blockIdx.x * 64;

    f32x4 z4 = {0.f, 0.f, 0.f, 0.f};
    f32x4 aa[4][2], ag[4][2];
#pragma unroll
    for (int i = 0; i < 4; ++i)
#pragma unroll
        for (int j = 0; j < 2; ++j) { aa[i][j] = z4; ag[i][j] = z4; }

    for (int kt = 0; kt < 512; kt += 64) {
        __syncthreads();
#pragma unroll
        for (int p = 0; p < 4; ++p) {
            int c   = tid + (p << 8);
            int row = c >> 3;
            int g   = (c & 7) ^ (row & 7);
            gld16(A + (size_t)(m0 + row) * 512 + kt + g * 8, As + c * 8);
        }
#pragma unroll
        for (int p = 0; p < 2; ++p) {
            int c   = tid + (p << 8);
            int row = c >> 3;
            int g   = (c & 7) ^ (row & 7);
            gld16(W1T + (size_t)(n0 + row) * 512 + kt + g * 8, Bsa + c * 8);
            gld16(W1T + (size_t)(1365 + n0 + row) * 512 + kt + g * 8, Bsg + c * 8);
        }
        __syncthreads();
#pragma unroll
        for (int ks = 0; ks < 2; ++ks) {
            bf16x8 af[4];
#pragma unroll
            for (int i = 0; i < 4; ++i) {
                int r = wm * 64 + i * 16 + l16;
                af[i] = *(const bf16x8*)(As + r * 64 + ((((ks << 2) + quad)) ^ (r & 7)) * 8);
            }
#pragma unroll
            for (int j = 0; j < 2; ++j) {
                int r = wn * 32 + j * 16 + l16;
                int sl = (((ks << 2) + quad)) ^ (r & 7);
                bf16x8 ba = *(const bf16x8*)(Bsa + r * 64 + sl * 8);
                bf16x8 bg = *(const bf16x8*)(Bsg + r * 64 + sl * 8);
#pragma unroll
                for (int i = 0; i < 4; ++i) {
                    aa[i][j] = MFMA16(af[i], ba, aa[i][j]);
                    ag[i][j] = MFMA16(af[i], bg, ag[i][j]);
                }
            }
        }
    }

#pragma unroll
    for (int i = 0; i < 4; ++i)
#pragma unroll
        for (int j = 0; j < 2; ++j)
#pragma unroll
            for (int r = 0; r < 4; ++r) {
                int m  = m0 + wm * 64 + i * 16 + quad * 4 + r;
                int n  = n0 + wn * 32 + j * 16 + l16;
                bf16 outv = (bf16)0.f;
                if (n < 1365) {
                    float av = aa[i][j][r] + b1[n];
                    float gv = ag[i][j][r] + b1[1365 + n];
                    float gel = 0.5f * gv * (1.0f + erff(gv * 0.70710678118f));
                    outv = (bf16)(av * gel);
                }
                act[(size_t)m * 1408 + n] = outv;
            }
}

// ---------------------------------------------------------------------------
// Launch
// ---------------------------------------------------------------------------
extern "C" void kernel_launch(void* const* d_in, const int* in_sizes, int n_in,
                              void* d_out, int out_size, void* d_ws, size_t ws_size,
                              hipStream_t stream) {
    const float* x      = (const float*)d_in[0];
    const float* ln1g   = (const float*)d_in[1];
    const float* ln1b   = (const float*)d_in[2];
    const float* Wqkv   = (const float*)d_in[3];
    const float* qscale = (const float*)d_in[4];
    const float* kscale = (const float*)d_in[5];
    const float* Wout   = (const float*)d_in[6];
    const float* ln2g   = (const float*)d_in[7];
    const float* ln2b   = (const float*)d_in[8];
    const float* W1     = (const float*)d_in[9];
    const float* b1     = (const float*)d_in[10];
    const float* W2     = (const float*)d_in[11];
    const float* b2     = (const float*)d_in[12];
    float* out = (float*)d_out;

    char* ws = (char*)d_ws;
    const size_t MB = 1024 * 1024;
    bf16* h   = (bf16*)(ws);             // 16 MB (reused: attn out o, then h2)
    bf16* qb  = (bf16*)(ws + 16 * MB);   // q/k/v contiguous 16..64 MB
    bf16* kb  = (bf16*)(ws + 32 * MB);
    bf16* vb  = (bf16*)(ws + 48 * MB);
    bf16* wts = (bf16*)(ws + 64 * MB);   // bf16 transposed weights, ~6.2 MB
    bf16* WqkvT = wts;                   // [1536][512]
    bf16* WoutT = WqkvT + 1536 * 512;    // [512][512]
    bf16* W1T   = WoutT + 512 * 512;     // [2816][512] (rows >=2730 zero)
    bf16* W2T   = W1T + 2816 * 512;      // [512][1408] (cols >=1365 zero)
    bf16* ob  = h;
    bf16* h2  = h;
    bf16* act = qb;                      // 46.2 MB over dead q/k/v
    float* x1 = out;                     // pre-FF residual lives in d_out

    // 0. merged prep: LN1 + all 4 weight transposes in one dispatch
    prep_kernel<<<4096 + 768 + 256 + 1408 + 704, 256, 0, stream>>>(
        x, ln1g, ln1b, h, Wqkv, WqkvT, Wout, WoutT, W1, W1T, W2, W2T);
    // 1. QKV GEMM with fused l2norm+scale+rotary epilogue -> per-head q/k/v
    gemm_bt<0><<<dim3(12, 128), 256, 0, stream>>>(h, WqkvT, 512, qb, nullptr,
                                                  qscale, kscale);
    // 2. local attention (128-row q-tiles, XCD-swizzled flat grid)
    attn_kernel<<<1024, 256, 0, stream>>>(qb, kb, vb, ob);
    // 3. out-proj + residual -> x1 (d_out, fp32)
    gemm_bt<1><<<dim3(4, 128), 256, 0, stream>>>(ob, WoutT, 512, nullptr, x1, x, nullptr);
    // 4. LN2 (reads d_out)
    ln_kernel<<<4096, 256, 0, stream>>>(x1, ln2g, ln2b, h2);
    // 5. FF1 fused dual-half + exact gelu -> act
    ff1_kernel<<<dim3(22, 128), 256, 0, stream>>>(h2, W1T, b1, act);
    // 6. FF2 + b2 + residual (in-place on d_out)
    gemm_bt<2><<<dim3(4, 128), 256, 0, stream>>>(act, W2T, 1408, nullptr, out, x1, b2);
}

// Round 7
// 350.377 us; speedup vs baseline: 1.2411x; 1.1047x over previous
//
#include <hip/hip_runtime.h>
#include <cstdint>
#include <cstddef>

typedef __bf16 bf16;
typedef __bf16 bf16x8 __attribute__((ext_vector_type(8)));
typedef float  f32x4  __attribute__((ext_vector_type(4)));

#define MFMA16(a, b, c) __builtin_amdgcn_mfma_f32_16x16x32_bf16((a), (b), (c), 0, 0, 0)

// async global->LDS, 16B per lane; data lands at wave-uniform base + lane*16
static __device__ __forceinline__ void gld16(const bf16* g, bf16* l) {
    __builtin_amdgcn_global_load_lds(
        (const __attribute__((address_space(1))) void*)g,
        (__attribute__((address_space(3))) void*)l, 16, 0, 0);
}

static __device__ __forceinline__ unsigned pack_bf16x2(bf16 a, bf16 b) {
    union { unsigned u; bf16 h[2]; } t;
    t.h[0] = a; t.h[1] = b;
    return t.u;
}

// ---------------------------------------------------------------------------
// Merged prep: LN1 (blocks 0..4095) + 4 weight transposes/converts
// (fp32 [K][N] -> bf16 [Nrows][Kpad], zero-padded) in one dispatch.
// ---------------------------------------------------------------------------
static __device__ __forceinline__ void tcvt_block(const float* __restrict__ src,
                                                  bf16* __restrict__ dst,
                                                  int K, int N, int Kpad, int Nrows,
                                                  int bkx, int bny, int tid,
                                                  float (*t)[33]) {
    int tx = tid & 31, ty = tid >> 5;
    int k0 = bkx * 32, n0 = bny * 32;
#pragma unroll
    for (int i = ty; i < 32; i += 8) {
        int k = k0 + i, n = n0 + tx;
        t[i][tx] = (k < K && n < N) ? src[(size_t)k * N + n] : 0.f;
    }
    __syncthreads();
#pragma unroll
    for (int i = ty; i < 32; i += 8) {
        int n = n0 + i, k = k0 + tx;
        if (n < Nrows && k < Kpad) dst[(size_t)n * Kpad + k] = (bf16)t[tx][i];
    }
}

__global__ __launch_bounds__(256) void prep_kernel(
    const float* __restrict__ x, const float* __restrict__ g,
    const float* __restrict__ b, bf16* __restrict__ h,
    const float* __restrict__ Wqkv, bf16* __restrict__ WqkvT,
    const float* __restrict__ Wout, bf16* __restrict__ WoutT,
    const float* __restrict__ W1, bf16* __restrict__ W1T,
    const float* __restrict__ W2, bf16* __restrict__ W2T) {
    __shared__ float t[32][33];
    const int bid = blockIdx.x;
    const int tid = threadIdx.x;
    if (bid < 4096) {
        // LayerNorm: one wave per 512-element row
        int row  = bid * 4 + (tid >> 6);
        int lane = tid & 63;
        const float* xr = x + (size_t)row * 512 + lane * 8;
        float4 v0 = *(const float4*)xr;
        float4 v1 = *(const float4*)(xr + 4);
        float s  = v0.x + v0.y + v0.z + v0.w + v1.x + v1.y + v1.z + v1.w;
        float ss = v0.x*v0.x + v0.y*v0.y + v0.z*v0.z + v0.w*v0.w
                 + v1.x*v1.x + v1.y*v1.y + v1.z*v1.z + v1.w*v1.w;
#pragma unroll
        for (int off = 1; off < 64; off <<= 1) {
            s  += __shfl_xor(s, off, 64);
            ss += __shfl_xor(ss, off, 64);
        }
        float mean = s * (1.0f / 512.0f);
        float var  = ss * (1.0f / 512.0f) - mean * mean;
        float rstd = rsqrtf(var + 1e-5f);
        const float* gr = g + lane * 8;
        const float* br = b + lane * 8;
        float4 g0 = *(const float4*)gr, g1 = *(const float4*)(gr + 4);
        float4 b0 = *(const float4*)br, b1 = *(const float4*)(br + 4);
        bf16x8 o;
        o[0] = (bf16)((v0.x - mean) * rstd * g0.x + b0.x);
        o[1] = (bf16)((v0.y - mean) * rstd * g0.y + b0.y);
        o[2] = (bf16)((v0.z - mean) * rstd * g0.z + b0.z);
        o[3] = (bf16)((v0.w - mean) * rstd * g0.w + b0.w);
        o[4] = (bf16)((v1.x - mean) * rstd * g1.x + b1.x);
        o[5] = (bf16)((v1.y - mean) * rstd * g1.y + b1.y);
        o[6] = (bf16)((v1.z - mean) * rstd * g1.z + b1.z);
        o[7] = (bf16)((v1.w - mean) * rstd * g1.w + b1.w);
        *(uint4*)(h + (size_t)row * 512 + lane * 8) = *(uint4*)&o;
    } else if (bid < 4096 + 768) {          // Wqkv: 16 x 48
        int bb = bid - 4096;
        tcvt_block(Wqkv, WqkvT, 512, 1536, 512, 1536, bb & 15, bb >> 4, tid, t);
    } else if (bid < 4096 + 768 + 256) {    // Wout: 16 x 16
        int bb = bid - (4096 + 768);
        tcvt_block(Wout, WoutT, 512, 512, 512, 512, bb & 15, bb >> 4, tid, t);
    } else if (bid < 4096 + 768 + 256 + 1408) {  // W1: 16 x 88
        int bb = bid - (4096 + 768 + 256);
        tcvt_block(W1, W1T, 512, 2730, 512, 2816, bb & 15, bb >> 4, tid, t);
    } else {                                 // W2: 44 x 16
        int bb = bid - (4096 + 768 + 256 + 1408);
        tcvt_block(W2, W2T, 1365, 512, 1408, 512, bb % 44, bb / 44, tid, t);
    }
}

// ---------------------------------------------------------------------------
// LayerNorm (standalone, for LN2): one wave per 512-element row
// ---------------------------------------------------------------------------
__global__ __launch_bounds__(256) void ln_kernel(const float* __restrict__ x,
                                                 const float* __restrict__ g,
                                                 const float* __restrict__ b,
                                                 bf16* __restrict__ out) {
    int row  = blockIdx.x * 4 + (threadIdx.x >> 6);
    int lane = threadIdx.x & 63;
    const float* xr = x + (size_t)row * 512 + lane * 8;
    float4 v0 = *(const float4*)xr;
    float4 v1 = *(const float4*)(xr + 4);
    float s  = v0.x + v0.y + v0.z + v0.w + v1.x + v1.y + v1.z + v1.w;
    float ss = v0.x*v0.x + v0.y*v0.y + v0.z*v0.z + v0.w*v0.w
             + v1.x*v1.x + v1.y*v1.y + v1.z*v1.z + v1.w*v1.w;
#pragma unroll
    for (int off = 1; off < 64; off <<= 1) {
        s  += __shfl_xor(s, off, 64);
        ss += __shfl_xor(ss, off, 64);
    }
    float mean = s * (1.0f / 512.0f);
    float var  = ss * (1.0f / 512.0f) - mean * mean;
    float rstd = rsqrtf(var + 1e-5f);
    const float* gr = g + lane * 8;
    const float* br = b + lane * 8;
    float4 g0 = *(const float4*)gr, g1 = *(const float4*)(gr + 4);
    float4 b0 = *(const float4*)br, b1 = *(const float4*)(br + 4);
    bf16x8 o;
    o[0] = (bf16)((v0.x - mean) * rstd * g0.x + b0.x);
    o[1] = (bf16)((v0.y - mean) * rstd * g0.y + b0.y);
    o[2] = (bf16)((v0.z - mean) * rstd * g0.z + b0.z);
    o[3] = (bf16)((v0.w - mean) * rstd * g0.w + b0.w);
    o[4] = (bf16)((v1.x - mean) * rstd * g1.x + b1.x);
    o[5] = (bf16)((v1.y - mean) * rstd * g1.y + b1.y);
    o[6] = (bf16)((v1.z - mean) * rstd * g1.z + b1.z);
    o[7] = (bf16)((v1.w - mean) * rstd * g1.w + b1.w);
    *(uint4*)(out + (size_t)row * 512 + lane * 8) = *(uint4*)&o;
}

// ---------------------------------------------------------------------------
// m97-style bf16 GEMM, 128x128 tile: A [M][K], B [N][K] bf16.
// EPI 0: fused l2norm + qk-scale + xPos rotary epilogue -> q/k/v scatter
//        (min-waves 3: transcendental epilogue needs registers)
// EPI 1: Cf = acc + res            (min-waves 4: occupancy squeeze)
// EPI 2: Cf = acc + res + bias[n]  (min-waves 4)
// ---------------------------------------------------------------------------
template <int EPI>
__global__ __launch_bounds__(256, (EPI == 0 ? 3 : 4)) void gemm_bt(
    const bf16* __restrict__ A, const bf16* __restrict__ Bm, int K,
    bf16* __restrict__ Cb, float* Cf,
    const float* res, const float* __restrict__ bias) {
    __shared__ __align__(16) bf16 As[128 * 64];
    __shared__ __align__(16) bf16 Bs[128 * 64];
    const int tid  = threadIdx.x;
    const int wid  = tid >> 6;
    const int lane = tid & 63;
    const int quad = lane >> 4;
    const int l16  = lane & 15;
    const int wm   = wid >> 1;
    const int wn   = wid & 1;
    const int m0   = blockIdx.y * 128;
    const int n0   = blockIdx.x * 128;

    f32x4 z4 = {0.f, 0.f, 0.f, 0.f};
    f32x4 acc[4][4];
#pragma unroll
    for (int i = 0; i < 4; ++i)
#pragma unroll
        for (int j = 0; j < 4; ++j) acc[i][j] = z4;

    for (int kt = 0; kt < K; kt += 64) {
        __syncthreads();
#pragma unroll
        for (int p = 0; p < 4; ++p) {
            int c   = tid + (p << 8);
            int row = c >> 3;
            int g   = (c & 7) ^ (row & 7);
            gld16(A  + (size_t)(m0 + row) * K + kt + g * 8, As + c * 8);
            gld16(Bm + (size_t)(n0 + row) * K + kt + g * 8, Bs + c * 8);
        }
        __syncthreads();
#pragma unroll
        for (int ks = 0; ks < 2; ++ks) {
            bf16x8 af[4], bfr[4];
#pragma unroll
            for (int i = 0; i < 4; ++i) {
                int r = wm * 64 + i * 16 + l16;
                af[i] = *(const bf16x8*)(As + r * 64 + ((((ks << 2) + quad)) ^ (r & 7)) * 8);
            }
#pragma unroll
            for (int j = 0; j < 4; ++j) {
                int r = wn * 64 + j * 16 + l16;
                bfr[j] = *(const bf16x8*)(Bs + r * 64 + ((((ks << 2) + quad)) ^ (r & 7)) * 8);
            }
#pragma unroll
            for (int i = 0; i < 4; ++i)
#pragma unroll
                for (int j = 0; j < 4; ++j)
                    acc[i][j] = MFMA16(af[i], bfr[j], acc[i][j]);
        }
    }

    if (EPI == 0) {
        // Wave-uniform: n-range [nbase, nbase+64) is head-aligned.
        const int nbase = n0 + wn * 64;
        const int which = nbase >> 9;     // 0=q, 1=k, 2=v
        const int hh    = (nbase >> 6) & 7;
        if (which == 2) {
#pragma unroll
            for (int i = 0; i < 4; ++i)
#pragma unroll
                for (int j = 0; j < 4; ++j)
#pragma unroll
                    for (int r = 0; r < 4; ++r) {
                        int m = m0 + wm * 64 + i * 16 + quad * 4 + r;
                        int d = j * 16 + l16;
                        int bb = m >> 13, nn = m & 8191;
                        Cb[(size_t)2 * 8388608 +
                           ((size_t)(bb * 8 + hh) * 8192 + nn) * 64 + d] =
                            (bf16)acc[i][j][r];
                    }
        } else {
            // l2norm + scale + xPos rotary, registers + DPP shuffles only.
            const float* scale = (which == 0) ? res : bias;  // qscale / kscale
            const float sgn = (which == 0) ? 1.0f : -1.0f;   // xs vs 1/xs
            float sc[4], revf[4], lg[4];
#pragma unroll
            for (int j = 0; j < 4; ++j) {
                int d  = j * 16 + l16;
                int i2 = d & 31;
                sc[j]   = scale[d];
                // 10000^(-i2/32) / (2*pi)
                revf[j] = __builtin_exp2f(-(float)i2 * 0.4152410118609190f) *
                          0.15915494309189535f;
                lg[j]   = __builtin_log2f(((float)(2 * i2) + 25.6f) * (1.0f / 89.6f));
            }
            const size_t obase = (size_t)which * 8388608;
#pragma unroll
            for (int i = 0; i < 4; ++i)
#pragma unroll
                for (int r = 0; r < 4; ++r) {
                    int m = m0 + wm * 64 + i * 16 + quad * 4 + r;
                    int bb = m >> 13, nn = m & 8191;
                    float ss = 0.f;
#pragma unroll
                    for (int j = 0; j < 4; ++j) ss += acc[i][j][r] * acc[i][j][r];
                    ss += __shfl_xor(ss, 1, 64);
                    ss += __shfl_xor(ss, 2, 64);
                    ss += __shfl_xor(ss, 4, 64);
                    ss += __shfl_xor(ss, 8, 64);
                    float rn = rsqrtf(fmaxf(ss, 1e-24f));
                    float val[4];
#pragma unroll
                    for (int j = 0; j < 4; ++j) val[j] = acc[i][j][r] * rn * sc[j];
                    float fn = (float)nn;
                    float pw = (fn - 4096.0f) * (1.0f / 256.0f) * sgn;
#pragma unroll
                    for (int j = 0; j < 4; ++j) {
                        float xrev = fn * revf[j];
                        xrev -= floorf(xrev);
                        float cv = __builtin_amdgcn_cosf(xrev);
                        float sv = __builtin_amdgcn_sinf(xrev);
                        float xs = __builtin_exp2f(pw * lg[j]);
                        float rh = (j < 2) ? -val[j ^ 2] : val[j ^ 2];
                        float ov = (val[j] * cv + rh * sv) * xs;
                        int d = j * 16 + l16;
                        Cb[obase + ((size_t)(bb * 8 + hh) * 8192 + nn) * 64 + d] =
                            (bf16)ov;
                    }
                }
        }
    } else {
#pragma unroll
        for (int i = 0; i < 4; ++i)
#pragma unroll
            for (int j = 0; j < 4; ++j)
#pragma unroll
                for (int r = 0; r < 4; ++r) {
                    int m = m0 + wm * 64 + i * 16 + quad * 4 + r;
                    int n = n0 + wn * 64 + j * 16 + l16;
                    float v = acc[i][j][r];
                    size_t idx = (size_t)m * 512 + n;
                    if (EPI == 1) {
                        Cf[idx] = v + res[idx];
                    } else {
                        float rv = res[idx];
                        Cf[idx] = v + rv + bias[n];
                    }
                }
    }
}

// ---------------------------------------------------------------------------
// Local windowed attention, fixed-max softmax (|s| <= 8 by construction).
// Block = 128 q-rows, wave = 32 rows (2 m-tiles). K/V chunks of 128 in LDS.
// ---------------------------------------------------------------------------
__global__ __launch_bounds__(256) void attn_kernel(const bf16* __restrict__ q,
                                                   const bf16* __restrict__ k,
                                                   const bf16* __restrict__ v,
                                                   bf16* __restrict__ o) {
    __shared__ __align__(16) bf16 Ks[128 * 64];
    __shared__ __align__(16) bf16 Vt[64][136];
    __shared__ __align__(16) bf16 Ps[4][16][136];
    const int tid  = threadIdx.x;
    const int wid  = tid >> 6;
    const int lane = tid & 63;
    const int quad = lane >> 4;
    const int l16  = lane & 15;
    const int lid = (blockIdx.x & 7) * 128 + (blockIdx.x >> 3);
    const int bh  = lid >> 6;
    const int q0  = (lid & 63) * 128;
    const size_t base = (size_t)bh * 8192;

    bf16x8 aq[2][2];
#pragma unroll
    for (int mt = 0; mt < 2; ++mt) {
        int qrow = q0 + wid * 32 + mt * 16 + l16;
        const bf16* qp = q + (base + qrow) * 64 + quad * 8;
        aq[mt][0] = *(const bf16x8*)qp;
        aq[mt][1] = *(const bf16x8*)(qp + 32);
    }
    f32x4 z4 = {0.f, 0.f, 0.f, 0.f};
    f32x4 accO[2][4];
    float rs[2][4];
#pragma unroll
    for (int mt = 0; mt < 2; ++mt)
#pragma unroll
        for (int j = 0; j < 4; ++j) { accO[mt][j] = z4; rs[mt][j] = 0.f; }

    int klo = q0 - 512;
    if (klo < 0) klo = 0;
    for (int kc = klo; kc < q0 + 128; kc += 128) {
        __syncthreads();
#pragma unroll
        for (int p = 0; p < 4; ++p) {
            int c   = tid + (p << 8);
            int row = c >> 3;
            int g   = (c & 7) ^ (row & 7);
            gld16(k + (base + kc + row) * 64 + g * 8, Ks + c * 8);
        }
        {
            int kp = lane;
#pragma unroll
            for (int w2 = 0; w2 < 2; ++w2) {
                int dc = wid * 2 + w2;
                const bf16* vp = v + (base + kc + kp * 2) * 64 + dc * 8;
                union { uint4 u; bf16 h[8]; } va, vb2;
                va.u  = *(const uint4*)vp;
                vb2.u = *(const uint4*)(vp + 64);
#pragma unroll
                for (int j = 0; j < 8; ++j)
                    *(unsigned*)&Vt[dc * 8 + j][kp * 2] =
                        pack_bf16x2(va.h[j], vb2.h[j]);
            }
        }
        __syncthreads();
#pragma unroll
        for (int mt = 0; mt < 2; ++mt) {
            f32x4 s[8];
#pragma unroll
            for (int ns = 0; ns < 8; ++ns) {
                int row = ns * 16 + l16;
                bf16x8 b0 = *(const bf16x8*)(Ks + row * 64 + ((quad    ) ^ (row & 7)) * 8);
                bf16x8 b1 = *(const bf16x8*)(Ks + row * 64 + ((4 + quad) ^ (row & 7)) * 8);
                f32x4 t = z4;
                t = MFMA16(aq[mt][0], b0, t);
                t = MFMA16(aq[mt][1], b1, t);
                s[ns] = t;
            }
            int gi0 = q0 + wid * 32 + mt * 16 + quad * 4;
#pragma unroll
            for (int ns = 0; ns < 8; ++ns) {
                int gj = kc + ns * 16 + l16;
#pragma unroll
                for (int r = 0; r < 4; ++r) {
                    int e = gi0 + r - gj;  // valid iff 0 <= e <= 512
                    float p = __builtin_exp2f(
                        fmaf(s[ns][r], 11.541560327f, -11.541560327f));
                    p = ((unsigned)e <= 512u) ? p : 0.f;
                    rs[mt][r] += p;
                    Ps[wid][quad * 4 + r][ns * 16 + l16] = (bf16)p;
                }
            }
#pragma unroll
            for (int ks2 = 0; ks2 < 4; ++ks2) {
                bf16x8 ap = *(const bf16x8*)&Ps[wid][l16][ks2 * 32 + quad * 8];
#pragma unroll
                for (int ds = 0; ds < 4; ++ds) {
                    bf16x8 bv = *(const bf16x8*)&Vt[ds * 16 + l16][ks2 * 32 + quad * 8];
                    accO[mt][ds] = MFMA16(ap, bv, accO[mt][ds]);
                }
            }
        }
    }
#pragma unroll
    for (int mt = 0; mt < 2; ++mt)
#pragma unroll
        for (int r = 0; r < 4; ++r) {
            float t = rs[mt][r];
            t += __shfl_xor(t, 1, 64);
            t += __shfl_xor(t, 2, 64);
            t += __shfl_xor(t, 4, 64);
            t += __shfl_xor(t, 8, 64);
            rs[mt][r] = 1.0f / t;
        }
    int bb = bh >> 3, hh = bh & 7;
#pragma unroll
    for (int mt = 0; mt < 2; ++mt)
#pragma unroll
        for (int ds = 0; ds < 4; ++ds)
#pragma unroll
            for (int r = 0; r < 4; ++r) {
                int m = q0 + wid * 32 + mt * 16 + quad * 4 + r;
                o[((size_t)(bb * 8192 + m)) * 512 + hh * 64 + ds * 16 + l16] =
                    (bf16)(accO[mt][ds][r] * rs[mt][r]);
            }
}

// ---------------------------------------------------------------------------
// FF1: fused dual-half (a + gate) GEMM + exact GELU -> act [16384][1408] bf16.
// 128(m) x 64(n per half) block tile; min-waves 4 occupancy squeeze.
// ---------------------------------------------------------------------------
__global__ __launch_bounds__(256, 4) void ff1_kernel(const bf16* __restrict__ A,
                                                     const bf16* __restrict__ W1T,
                                                     const float* __restrict__ b1,
                                                     bf16* __restrict__ act) {
    __shared__ __align__(16) bf16 As[128 * 64];
    __shared__ __align__(16) bf16 Bsa[64 * 64];
    __shared__ __align__(16) bf16 Bsg[64 * 64];
    const int tid  = threadIdx.x;
    const int wid  = tid >> 6;
    const int lane = tid & 63;
    const int quad = lane >> 4;
    const int l16  = lane & 15;
    const int wm   = wid >> 1;
    const int wn   = wid & 1;
    const int m0   = blockIdx.y * 128;
    const int n0   = blockIdx.x * 64;

    f32x4 z4 = {0.f, 0.f, 0.f, 0.f};
    f32x4 aa[4][2], ag[4][2];
#pragma unroll
    for (int i = 0; i < 4; ++i)
#pragma unroll
        for (int j = 0; j < 2; ++j) { aa[i][j] = z4; ag[i][j] = z4; }

    for (int kt = 0; kt < 512; kt += 64) {
        __syncthreads();
#pragma unroll
        for (int p = 0; p < 4; ++p) {
            int c   = tid + (p << 8);
            int row = c >> 3;
            int g   = (c & 7) ^ (row & 7);
            gld16(A + (size_t)(m0 + row) * 512 + kt + g * 8, As + c * 8);
        }
#pragma unroll
        for (int p = 0; p < 2; ++p) {
            int c   = tid + (p << 8);
            int row = c >> 3;
            int g   = (c & 7) ^ (row & 7);
            gld16(W1T + (size_t)(n0 + row) * 512 + kt + g * 8, Bsa + c * 8);
            gld16(W1T + (size_t)(1365 + n0 + row) * 512 + kt + g * 8, Bsg + c * 8);
        }
        __syncthreads();
#pragma unroll
        for (int ks = 0; ks < 2; ++ks) {
            bf16x8 af[4];
#pragma unroll
            for (int i = 0; i < 4; ++i) {
                int r = wm * 64 + i * 16 + l16;
                af[i] = *(const bf16x8*)(As + r * 64 + ((((ks << 2) + quad)) ^ (r & 7)) * 8);
            }
#pragma unroll
            for (int j = 0; j < 2; ++j) {
                int r = wn * 32 + j * 16 + l16;
                int sl = (((ks << 2) + quad)) ^ (r & 7);
                bf16x8 ba = *(const bf16x8*)(Bsa + r * 64 + sl * 8);
                bf16x8 bg = *(const bf16x8*)(Bsg + r * 64 + sl * 8);
#pragma unroll
                for (int i = 0; i < 4; ++i) {
                    aa[i][j] = MFMA16(af[i], ba, aa[i][j]);
                    ag[i][j] = MFMA16(af[i], bg, ag[i][j]);
                }
            }
        }
    }

#pragma unroll
    for (int i = 0; i < 4; ++i)
#pragma unroll
        for (int j = 0; j < 2; ++j)
#pragma unroll
            for (int r = 0; r < 4; ++r) {
                int m  = m0 + wm * 64 + i * 16 + quad * 4 + r;
                int n  = n0 + wn * 32 + j * 16 + l16;
                bf16 outv = (bf16)0.f;
                if (n < 1365) {
                    float av = aa[i][j][r] + b1[n];
                    float gv = ag[i][j][r] + b1[1365 + n];
                    float gel = 0.5f * gv * (1.0f + erff(gv * 0.70710678118f));
                    outv = (bf16)(av * gel);
                }
                act[(size_t)m * 1408 + n] = outv;
            }
}

// ---------------------------------------------------------------------------
// Launch
// ---------------------------------------------------------------------------
extern "C" void kernel_launch(void* const* d_in, const int* in_sizes, int n_in,
                              void* d_out, int out_size, void* d_ws, size_t ws_size,
                              hipStream_t stream) {
    const float* x      = (const float*)d_in[0];
    const float* ln1g   = (const float*)d_in[1];
    const float* ln1b   = (const float*)d_in[2];
    const float* Wqkv   = (const float*)d_in[3];
    const float* qscale = (const float*)d_in[4];
    const float* kscale = (const float*)d_in[5];
    const float* Wout   = (const float*)d_in[6];
    const float* ln2g   = (const float*)d_in[7];
    const float* ln2b   = (const float*)d_in[8];
    const float* W1     = (const float*)d_in[9];
    const float* b1     = (const float*)d_in[10];
    const float* W2     = (const float*)d_in[11];
    const float* b2     = (const float*)d_in[12];
    float* out = (float*)d_out;

    char* ws = (char*)d_ws;
    const size_t MB = 1024 * 1024;
    bf16* h   = (bf16*)(ws);             // 16 MB (reused: attn out o, then h2)
    bf16* qb  = (bf16*)(ws + 16 * MB);   // q/k/v contiguous 16..64 MB
    bf16* kb  = (bf16*)(ws + 32 * MB);
    bf16* vb  = (bf16*)(ws + 48 * MB);
    bf16* wts = (bf16*)(ws + 64 * MB);   // bf16 transposed weights, ~6.2 MB
    bf16* WqkvT = wts;                   // [1536][512]
    bf16* WoutT = WqkvT + 1536 * 512;    // [512][512]
    bf16* W1T   = WoutT + 512 * 512;     // [2816][512] (rows >=2730 zero)
    bf16* W2T   = W1T + 2816 * 512;      // [512][1408] (cols >=1365 zero)
    bf16* ob  = h;
    bf16* h2  = h;
    bf16* act = qb;                      // 46.2 MB over dead q/k/v
    float* x1 = out;                     // pre-FF residual lives in d_out

    // 0. merged prep: LN1 + all 4 weight transposes in one dispatch
    prep_kernel<<<4096 + 768 + 256 + 1408 + 704, 256, 0, stream>>>(
        x, ln1g, ln1b, h, Wqkv, WqkvT, Wout, WoutT, W1, W1T, W2, W2T);
    // 1. QKV GEMM with fused l2norm+scale+rotary epilogue -> per-head q/k/v
    gemm_bt<0><<<dim3(12, 128), 256, 0, stream>>>(h, WqkvT, 512, qb, nullptr,
                                                  qscale, kscale);
    // 2. local attention (128-row q-tiles, XCD-swizzled flat grid)
    attn_kernel<<<1024, 256, 0, stream>>>(qb, kb, vb, ob);
    // 3. out-proj + residual -> x1 (d_out, fp32)
    gemm_bt<1><<<dim3(4, 128), 256, 0, stream>>>(ob, WoutT, 512, nullptr, x1, x, nullptr);
    // 4. LN2 (reads d_out)
    ln_kernel<<<4096, 256, 0, stream>>>(x1, ln2g, ln2b, h2);
    // 5. FF1 fused dual-half + exact gelu -> act
    ff1_kernel<<<dim3(22, 128), 256, 0, stream>>>(h2, W1T, b1, act);
    // 6. FF2 + b2 + residual (in-place on d_out)
    gemm_bt<2><<<dim3(4, 128), 256, 0, stream>>>(act, W2T, 1408, nullptr, out, x1, b2);
}

// Round 8
// 346.050 us; speedup vs baseline: 1.2566x; 1.0125x over previous
//
#include <hip/hip_runtime.h>
#include <cstdint>
#include <cstddef>

typedef __bf16 bf16;
typedef __bf16 bf16x8 __attribute__((ext_vector_type(8)));
typedef float  f32x4  __attribute__((ext_vector_type(4)));

#define MFMA16(a, b, c) __builtin_amdgcn_mfma_f32_16x16x32_bf16((a), (b), (c), 0, 0, 0)

// async global->LDS, 16B per lane; data lands at wave-uniform base + lane*16
static __device__ __forceinline__ void gld16(const bf16* g, bf16* l) {
    __builtin_amdgcn_global_load_lds(
        (const __attribute__((address_space(1))) void*)g,
        (__attribute__((address_space(3))) void*)l, 16, 0, 0);
}

static __device__ __forceinline__ unsigned pack_bf16x2(bf16 a, bf16 b) {
    union { unsigned u; bf16 h[2]; } t;
    t.h[0] = a; t.h[1] = b;
    return t.u;
}

// ---------------------------------------------------------------------------
// Merged prep: LN1 (blocks 0..4095) + 4 weight transposes/converts
// (fp32 [K][N] -> bf16 [Nrows][Kpad], zero-padded) in one dispatch.
// ---------------------------------------------------------------------------
static __device__ __forceinline__ void tcvt_block(const float* __restrict__ src,
                                                  bf16* __restrict__ dst,
                                                  int K, int N, int Kpad, int Nrows,
                                                  int bkx, int bny, int tid,
                                                  float (*t)[33]) {
    int tx = tid & 31, ty = tid >> 5;
    int k0 = bkx * 32, n0 = bny * 32;
#pragma unroll
    for (int i = ty; i < 32; i += 8) {
        int k = k0 + i, n = n0 + tx;
        t[i][tx] = (k < K && n < N) ? src[(size_t)k * N + n] : 0.f;
    }
    __syncthreads();
#pragma unroll
    for (int i = ty; i < 32; i += 8) {
        int n = n0 + i, k = k0 + tx;
        if (n < Nrows && k < Kpad) dst[(size_t)n * Kpad + k] = (bf16)t[tx][i];
    }
}

__global__ __launch_bounds__(256) void prep_kernel(
    const float* __restrict__ x, const float* __restrict__ g,
    const float* __restrict__ b, bf16* __restrict__ h,
    const float* __restrict__ Wqkv, bf16* __restrict__ WqkvT,
    const float* __restrict__ Wout, bf16* __restrict__ WoutT,
    const float* __restrict__ W1, bf16* __restrict__ W1T,
    const float* __restrict__ W2, bf16* __restrict__ W2T) {
    __shared__ float t[32][33];
    const int bid = blockIdx.x;
    const int tid = threadIdx.x;
    if (bid < 4096) {
        // LayerNorm: one wave per 512-element row
        int row  = bid * 4 + (tid >> 6);
        int lane = tid & 63;
        const float* xr = x + (size_t)row * 512 + lane * 8;
        float4 v0 = *(const float4*)xr;
        float4 v1 = *(const float4*)(xr + 4);
        float s  = v0.x + v0.y + v0.z + v0.w + v1.x + v1.y + v1.z + v1.w;
        float ss = v0.x*v0.x + v0.y*v0.y + v0.z*v0.z + v0.w*v0.w
                 + v1.x*v1.x + v1.y*v1.y + v1.z*v1.z + v1.w*v1.w;
#pragma unroll
        for (int off = 1; off < 64; off <<= 1) {
            s  += __shfl_xor(s, off, 64);
            ss += __shfl_xor(ss, off, 64);
        }
        float mean = s * (1.0f / 512.0f);
        float var  = ss * (1.0f / 512.0f) - mean * mean;
        float rstd = rsqrtf(var + 1e-5f);
        const float* gr = g + lane * 8;
        const float* br = b + lane * 8;
        float4 g0 = *(const float4*)gr, g1 = *(const float4*)(gr + 4);
        float4 b0 = *(const float4*)br, b1 = *(const float4*)(br + 4);
        bf16x8 o;
        o[0] = (bf16)((v0.x - mean) * rstd * g0.x + b0.x);
        o[1] = (bf16)((v0.y - mean) * rstd * g0.y + b0.y);
        o[2] = (bf16)((v0.z - mean) * rstd * g0.z + b0.z);
        o[3] = (bf16)((v0.w - mean) * rstd * g0.w + b0.w);
        o[4] = (bf16)((v1.x - mean) * rstd * g1.x + b1.x);
        o[5] = (bf16)((v1.y - mean) * rstd * g1.y + b1.y);
        o[6] = (bf16)((v1.z - mean) * rstd * g1.z + b1.z);
        o[7] = (bf16)((v1.w - mean) * rstd * g1.w + b1.w);
        *(uint4*)(h + (size_t)row * 512 + lane * 8) = *(uint4*)&o;
    } else if (bid < 4096 + 768) {          // Wqkv: 16 x 48
        int bb = bid - 4096;
        tcvt_block(Wqkv, WqkvT, 512, 1536, 512, 1536, bb & 15, bb >> 4, tid, t);
    } else if (bid < 4096 + 768 + 256) {    // Wout: 16 x 16
        int bb = bid - (4096 + 768);
        tcvt_block(Wout, WoutT, 512, 512, 512, 512, bb & 15, bb >> 4, tid, t);
    } else if (bid < 4096 + 768 + 256 + 1408) {  // W1: 16 x 88
        int bb = bid - (4096 + 768 + 256);
        tcvt_block(W1, W1T, 512, 2730, 512, 2816, bb & 15, bb >> 4, tid, t);
    } else {                                 // W2: 44 x 16
        int bb = bid - (4096 + 768 + 256 + 1408);
        tcvt_block(W2, W2T, 1365, 512, 1408, 512, bb % 44, bb / 44, tid, t);
    }
}

// ---------------------------------------------------------------------------
// LayerNorm (standalone, for LN2): one wave per 512-element row
// ---------------------------------------------------------------------------
__global__ __launch_bounds__(256) void ln_kernel(const float* __restrict__ x,
                                                 const float* __restrict__ g,
                                                 const float* __restrict__ b,
                                                 bf16* __restrict__ out) {
    int row  = blockIdx.x * 4 + (threadIdx.x >> 6);
    int lane = threadIdx.x & 63;
    const float* xr = x + (size_t)row * 512 + lane * 8;
    float4 v0 = *(const float4*)xr;
    float4 v1 = *(const float4*)(xr + 4);
    float s  = v0.x + v0.y + v0.z + v0.w + v1.x + v1.y + v1.z + v1.w;
    float ss = v0.x*v0.x + v0.y*v0.y + v0.z*v0.z + v0.w*v0.w
             + v1.x*v1.x + v1.y*v1.y + v1.z*v1.z + v1.w*v1.w;
#pragma unroll
    for (int off = 1; off < 64; off <<= 1) {
        s  += __shfl_xor(s, off, 64);
        ss += __shfl_xor(ss, off, 64);
    }
    float mean = s * (1.0f / 512.0f);
    float var  = ss * (1.0f / 512.0f) - mean * mean;
    float rstd = rsqrtf(var + 1e-5f);
    const float* gr = g + lane * 8;
    const float* br = b + lane * 8;
    float4 g0 = *(const float4*)gr, g1 = *(const float4*)(gr + 4);
    float4 b0 = *(const float4*)br, b1 = *(const float4*)(br + 4);
    bf16x8 o;
    o[0] = (bf16)((v0.x - mean) * rstd * g0.x + b0.x);
    o[1] = (bf16)((v0.y - mean) * rstd * g0.y + b0.y);
    o[2] = (bf16)((v0.z - mean) * rstd * g0.z + b0.z);
    o[3] = (bf16)((v0.w - mean) * rstd * g0.w + b0.w);
    o[4] = (bf16)((v1.x - mean) * rstd * g1.x + b1.x);
    o[5] = (bf16)((v1.y - mean) * rstd * g1.y + b1.y);
    o[6] = (bf16)((v1.z - mean) * rstd * g1.z + b1.z);
    o[7] = (bf16)((v1.w - mean) * rstd * g1.w + b1.w);
    *(uint4*)(out + (size_t)row * 512 + lane * 8) = *(uint4*)&o;
}

// ---------------------------------------------------------------------------
// m97-style bf16 GEMM, 128x128 tile: A [M][K], B [N][K] bf16.
// EPI 0: fused l2norm + qk-scale + xPos rotary epilogue -> q/k/v scatter
// EPI 1: Cf = acc + res            (min-waves 4: occupancy squeeze)
// EPI 2: Cf = acc + res + bias[n]  (min-waves 4)
// ---------------------------------------------------------------------------
template <int EPI>
__global__ __launch_bounds__(256, (EPI == 0 ? 3 : 4)) void gemm_bt(
    const bf16* __restrict__ A, const bf16* __restrict__ Bm, int K,
    bf16* __restrict__ Cb, float* Cf,
    const float* res, const float* __restrict__ bias) {
    __shared__ __align__(16) bf16 As[128 * 64];
    __shared__ __align__(16) bf16 Bs[128 * 64];
    const int tid  = threadIdx.x;
    const int wid  = tid >> 6;
    const int lane = tid & 63;
    const int quad = lane >> 4;
    const int l16  = lane & 15;
    const int wm   = wid >> 1;
    const int wn   = wid & 1;
    const int m0   = blockIdx.y * 128;
    const int n0   = blockIdx.x * 128;

    f32x4 z4 = {0.f, 0.f, 0.f, 0.f};
    f32x4 acc[4][4];
#pragma unroll
    for (int i = 0; i < 4; ++i)
#pragma unroll
        for (int j = 0; j < 4; ++j) acc[i][j] = z4;

    for (int kt = 0; kt < K; kt += 64) {
        __syncthreads();
#pragma unroll
        for (int p = 0; p < 4; ++p) {
            int c   = tid + (p << 8);
            int row = c >> 3;
            int g   = (c & 7) ^ (row & 7);
            gld16(A  + (size_t)(m0 + row) * K + kt + g * 8, As + c * 8);
            gld16(Bm + (size_t)(n0 + row) * K + kt + g * 8, Bs + c * 8);
        }
        __syncthreads();
#pragma unroll
        for (int ks = 0; ks < 2; ++ks) {
            bf16x8 af[4], bfr[4];
#pragma unroll
            for (int i = 0; i < 4; ++i) {
                int r = wm * 64 + i * 16 + l16;
                af[i] = *(const bf16x8*)(As + r * 64 + ((((ks << 2) + quad)) ^ (r & 7)) * 8);
            }
#pragma unroll
            for (int j = 0; j < 4; ++j) {
                int r = wn * 64 + j * 16 + l16;
                bfr[j] = *(const bf16x8*)(Bs + r * 64 + ((((ks << 2) + quad)) ^ (r & 7)) * 8);
            }
#pragma unroll
            for (int i = 0; i < 4; ++i)
#pragma unroll
                for (int j = 0; j < 4; ++j)
                    acc[i][j] = MFMA16(af[i], bfr[j], acc[i][j]);
        }
    }

    if (EPI == 0) {
        // Wave-uniform: n-range [nbase, nbase+64) is head-aligned.
        const int nbase = n0 + wn * 64;
        const int which = nbase >> 9;     // 0=q, 1=k, 2=v
        const int hh    = (nbase >> 6) & 7;
        if (which == 2) {
#pragma unroll
            for (int i = 0; i < 4; ++i)
#pragma unroll
                for (int j = 0; j < 4; ++j)
#pragma unroll
                    for (int r = 0; r < 4; ++r) {
                        int m = m0 + wm * 64 + i * 16 + quad * 4 + r;
                        int d = j * 16 + l16;
                        int bb = m >> 13, nn = m & 8191;
                        Cb[(size_t)2 * 8388608 +
                           ((size_t)(bb * 8 + hh) * 8192 + nn) * 64 + d] =
                            (bf16)acc[i][j][r];
                    }
        } else {
            // l2norm + scale + xPos rotary, registers + DPP shuffles only.
            const float* scale = (which == 0) ? res : bias;  // qscale / kscale
            const float sgn = (which == 0) ? 1.0f : -1.0f;   // xs vs 1/xs
            float sc[4], revf[4], lg[4];
#pragma unroll
            for (int j = 0; j < 4; ++j) {
                int d  = j * 16 + l16;
                int i2 = d & 31;
                sc[j]   = scale[d];
                // 10000^(-i2/32) / (2*pi)
                revf[j] = __builtin_exp2f(-(float)i2 * 0.4152410118609190f) *
                          0.15915494309189535f;
                lg[j]   = __builtin_log2f(((float)(2 * i2) + 25.6f) * (1.0f / 89.6f));
            }
            const size_t obase = (size_t)which * 8388608;
#pragma unroll
            for (int i = 0; i < 4; ++i)
#pragma unroll
                for (int r = 0; r < 4; ++r) {
                    int m = m0 + wm * 64 + i * 16 + quad * 4 + r;
                    int bb = m >> 13, nn = m & 8191;
                    float ss = 0.f;
#pragma unroll
                    for (int j = 0; j < 4; ++j) ss += acc[i][j][r] * acc[i][j][r];
                    ss += __shfl_xor(ss, 1, 64);
                    ss += __shfl_xor(ss, 2, 64);
                    ss += __shfl_xor(ss, 4, 64);
                    ss += __shfl_xor(ss, 8, 64);
                    float rn = rsqrtf(fmaxf(ss, 1e-24f));
                    float val[4];
#pragma unroll
                    for (int j = 0; j < 4; ++j) val[j] = acc[i][j][r] * rn * sc[j];
                    float fn = (float)nn;
                    float pw = (fn - 4096.0f) * (1.0f / 256.0f) * sgn;
#pragma unroll
                    for (int j = 0; j < 4; ++j) {
                        float xrev = fn * revf[j];
                        xrev -= floorf(xrev);
                        float cv = __builtin_amdgcn_cosf(xrev);
                        float sv = __builtin_amdgcn_sinf(xrev);
                        float xs = __builtin_exp2f(pw * lg[j]);
                        float rh = (j < 2) ? -val[j ^ 2] : val[j ^ 2];
                        float ov = (val[j] * cv + rh * sv) * xs;
                        int d = j * 16 + l16;
                        Cb[obase + ((size_t)(bb * 8 + hh) * 8192 + nn) * 64 + d] =
                            (bf16)ov;
                    }
                }
        }
    } else {
#pragma unroll
        for (int i = 0; i < 4; ++i)
#pragma unroll
            for (int j = 0; j < 4; ++j)
#pragma unroll
                for (int r = 0; r < 4; ++r) {
                    int m = m0 + wm * 64 + i * 16 + quad * 4 + r;
                    int n = n0 + wn * 64 + j * 16 + l16;
                    float v = acc[i][j][r];
                    size_t idx = (size_t)m * 512 + n;
                    if (EPI == 1) {
                        Cf[idx] = v + res[idx];
                    } else {
                        float rv = res[idx];
                        Cf[idx] = v + rv + bias[n];
                    }
                }
    }
}

// ---------------------------------------------------------------------------
// Local windowed attention, fixed-max softmax (|s| <= 8 by construction).
// S^T formulation: MFMA(A=K-frag, B=Q-frag) puts the qrow on the C-layout
// column (thread-fixed) and 4 consecutive KEYS on the registers -> packed
// b64 P-writes, per-thread scalar row-sum. K-chunks of 64; 26 KB LDS;
// launch_bounds(256,4) -> 4 blocks/CU, grid 1024 = exactly 4/CU (no tail).
// ---------------------------------------------------------------------------
__global__ __launch_bounds__(256, 4) void attn_kernel(const bf16* __restrict__ q,
                                                      const bf16* __restrict__ k,
                                                      const bf16* __restrict__ v,
                                                      bf16* __restrict__ o) {
    __shared__ __align__(16) bf16 Ks[64 * 64];     // [key][d], XOR-swizzled
    __shared__ __align__(16) bf16 Vt[64][72];      // [d][key]
    __shared__ __align__(16) bf16 Ps[4][16][72];   // per-wave P [qrow][key]
    const int tid  = threadIdx.x;
    const int wid  = tid >> 6;
    const int lane = tid & 63;
    const int quad = lane >> 4;
    const int l16  = lane & 15;
    const int lid = (blockIdx.x & 7) * 128 + (blockIdx.x >> 3);
    const int bh  = lid >> 6;
    const int q0  = (lid & 63) * 128;
    const size_t base = (size_t)bh * 8192;
    const float CE = 11.541560327f;   // 8 / ln2

    // Q fragments (B-operand: n=qrow on l16)
    bf16x8 aq[2][2];
#pragma unroll
    for (int mt = 0; mt < 2; ++mt) {
        int qrow = q0 + wid * 32 + mt * 16 + l16;
        const bf16* qp = q + (base + qrow) * 64 + quad * 8;
        aq[mt][0] = *(const bf16x8*)qp;
        aq[mt][1] = *(const bf16x8*)(qp + 32);
    }
    f32x4 z4 = {0.f, 0.f, 0.f, 0.f};
    f32x4 accO[2][4];
    float rs[2] = {0.f, 0.f};
#pragma unroll
    for (int mt = 0; mt < 2; ++mt)
#pragma unroll
        for (int j = 0; j < 4; ++j) accO[mt][j] = z4;

    int klo = q0 - 512;
    if (klo < 0) klo = 0;
    for (int kc = klo; kc < q0 + 128; kc += 64) {
        __syncthreads();
        // K: async staging, XOR-swizzled 16B chunks (64 keys x 64 d)
#pragma unroll
        for (int p = 0; p < 2; ++p) {
            int c   = tid + (p << 8);
            int row = c >> 3;
            int g   = (c & 7) ^ (row & 7);
            gld16(k + (base + kc + row) * 64 + g * 8, Ks + c * 8);
        }
        // V transpose: thread (dc = tid>>5, kp = tid&31) handles keys 2kp,2kp+1
        {
            int dc = tid >> 5, kp = tid & 31;
            const bf16* vp = v + (base + kc + kp * 2) * 64 + dc * 8;
            union { uint4 u; bf16 h[8]; } va, vb2;
            va.u  = *(const uint4*)vp;
            vb2.u = *(const uint4*)(vp + 64);
#pragma unroll
            for (int j = 0; j < 8; ++j)
                *(unsigned*)&Vt[dc * 8 + j][kp * 2] = pack_bf16x2(va.h[j], vb2.h[j]);
        }
        __syncthreads();
#pragma unroll
        for (int mt = 0; mt < 2; ++mt) {
            const int qrow = q0 + wid * 32 + mt * 16 + l16;
            // S^T tiles: m=key (A=K-frag), n=qrow (B=Q-frag)
            f32x4 s[4];
#pragma unroll
            for (int ns = 0; ns < 4; ++ns) {
                int row = ns * 16 + l16;
                bf16x8 kf0 = *(const bf16x8*)(Ks + row * 64 + ((quad    ) ^ (row & 7)) * 8);
                bf16x8 kf1 = *(const bf16x8*)(Ks + row * 64 + ((4 + quad) ^ (row & 7)) * 8);
                f32x4 t = z4;
                t = MFMA16(kf0, aq[mt][0], t);
                t = MFMA16(kf1, aq[mt][1], t);
                s[ns] = t;
            }
            // p = exp(8s - 8), mask e = qrow-key in [0,512]; packed b64 write
#pragma unroll
            for (int ns = 0; ns < 4; ++ns) {
                int e0 = qrow - (kc + ns * 16 + quad * 4);
                float p[4];
#pragma unroll
                for (int r = 0; r < 4; ++r) {
                    float pv = __builtin_exp2f(fmaf(s[ns][r], CE, -CE));
                    p[r] = ((unsigned)(e0 - r) <= 512u) ? pv : 0.f;
                }
                rs[mt] += (p[0] + p[1]) + (p[2] + p[3]);
                union { uint2 v2; unsigned w[2]; } pk;
                pk.w[0] = pack_bf16x2((bf16)p[0], (bf16)p[1]);
                pk.w[1] = pack_bf16x2((bf16)p[2], (bf16)p[3]);
                *(uint2*)&Ps[wid][l16][ns * 16 + quad * 4] = pk.v2;
            }
            // O[mt] += P V (wave-private Ps; waitcnt ordering)
#pragma unroll
            for (int ks2 = 0; ks2 < 2; ++ks2) {
                bf16x8 ap = *(const bf16x8*)&Ps[wid][l16][ks2 * 32 + quad * 8];
#pragma unroll
                for (int ds = 0; ds < 4; ++ds) {
                    bf16x8 bv = *(const bf16x8*)&Vt[ds * 16 + l16][ks2 * 32 + quad * 8];
                    accO[mt][ds] = MFMA16(ap, bv, accO[mt][ds]);
                }
            }
        }
    }
    // row-sum: lanes sharing l16 (xor 16/32), then invert
#pragma unroll
    for (int mt = 0; mt < 2; ++mt) {
        float t = rs[mt];
        t += __shfl_xor(t, 16, 64);
        t += __shfl_xor(t, 32, 64);
        rs[mt] = 1.0f / t;
    }
    int bb = bh >> 3, hh = bh & 7;
#pragma unroll
    for (int mt = 0; mt < 2; ++mt)
#pragma unroll
        for (int r = 0; r < 4; ++r) {
            // accO row (qrow-sub = quad*4+r) needs rs held by lane l16==quad*4+r
            float inv = __shfl(rs[mt], quad * 4 + r, 64);
            int m = q0 + wid * 32 + mt * 16 + quad * 4 + r;
#pragma unroll
            for (int ds = 0; ds < 4; ++ds)
                o[((size_t)(bb * 8192 + m)) * 512 + hh * 64 + ds * 16 + l16] =
                    (bf16)(accO[mt][ds][r] * inv);
        }
}

// ---------------------------------------------------------------------------
// FF1: fused dual-half (a + gate) GEMM + exact GELU -> act [16384][1408] bf16.
// 128(m) x 64(n per half) block tile; min-waves 4 occupancy squeeze.
// ---------------------------------------------------------------------------
__global__ __launch_bounds__(256, 4) void ff1_kernel(const bf16* __restrict__ A,
                                                     const bf16* __restrict__ W1T,
                                                     const float* __restrict__ b1,
                                                     bf16* __restrict__ act) {
    __shared__ __align__(16) bf16 As[128 * 64];
    __shared__ __align__(16) bf16 Bsa[64 * 64];
    __shared__ __align__(16) bf16 Bsg[64 * 64];
    const int tid  = threadIdx.x;
    const int wid  = tid >> 6;
    const int lane = tid & 63;
    const int quad = lane >> 4;
    const int l16  = lane & 15;
    const int wm   = wid >> 1;
    const int wn   = wid & 1;
    const int m0   = blockIdx.y * 128;
    const int n0   = blockIdx.x * 64;

    f32x4 z4 = {0.f, 0.f, 0.f, 0.f};
    f32x4 aa[4][2], ag[4][2];
#pragma unroll
    for (int i = 0; i < 4; ++i)
#pragma unroll
        for (int j = 0; j < 2; ++j) { aa[i][j] = z4; ag[i][j] = z4; }

    for (int kt = 0; kt < 512; kt += 64) {
        __syncthreads();
#pragma unroll
        for (int p = 0; p < 4; ++p) {
            int c   = tid + (p << 8);
            int row = c >> 3;
            int g   = (c & 7) ^ (row & 7);
            gld16(A + (size_t)(m0 + row) * 512 + kt + g * 8, As + c * 8);
        }
#pragma unroll
        for (int p = 0; p < 2; ++p) {
            int c   = tid + (p << 8);
            int row = c >> 3;
            int g   = (c & 7) ^ (row & 7);
            gld16(W1T + (size_t)(n0 + row) * 512 + kt + g * 8, Bsa + c * 8);
            gld16(W1T + (size_t)(1365 + n0 + row) * 512 + kt + g * 8, Bsg + c * 8);
        }
        __syncthreads();
#pragma unroll
        for (int ks = 0; ks < 2; ++ks) {
            bf16x8 af[4];
#pragma unroll
            for (int i = 0; i < 4; ++i) {
                int r = wm * 64 + i * 16 + l16;
                af[i] = *(const bf16x8*)(As + r * 64 + ((((ks << 2) + quad)) ^ (r & 7)) * 8);
            }
#pragma unroll
            for (int j = 0; j < 2; ++j) {
                int r = wn * 32 + j * 16 + l16;
                int sl = (((ks << 2) + quad)) ^ (r & 7);
                bf16x8 ba = *(const bf16x8*)(Bsa + r * 64 + sl * 8);
                bf16x8 bg = *(const bf16x8*)(Bsg + r * 64 + sl * 8);
#pragma unroll
                for (int i = 0; i < 4; ++i) {
                    aa[i][j] = MFMA16(af[i], ba, aa[i][j]);
                    ag[i][j] = MFMA16(af[i], bg, ag[i][j]);
                }
            }
        }
    }

#pragma unroll
    for (int i = 0; i < 4; ++i)
#pragma unroll
        for (int j = 0; j < 2; ++j)
#pragma unroll
            for (int r = 0; r < 4; ++r) {
                int m  = m0 + wm * 64 + i * 16 + quad * 4 + r;
                int n  = n0 + wn * 32 + j * 16 + l16;
                bf16 outv = (bf16)0.f;
                if (n < 1365) {
                    float av = aa[i][j][r] + b1[n];
                    float gv = ag[i][j][r] + b1[1365 + n];
                    float gel = 0.5f * gv * (1.0f + erff(gv * 0.70710678118f));
                    outv = (bf16)(av * gel);
                }
                act[(size_t)m * 1408 + n] = outv;
            }
}

// ---------------------------------------------------------------------------
// Launch
// ---------------------------------------------------------------------------
extern "C" void kernel_launch(void* const* d_in, const int* in_sizes, int n_in,
                              void* d_out, int out_size, void* d_ws, size_t ws_size,
                              hipStream_t stream) {
    const float* x      = (const float*)d_in[0];
    const float* ln1g   = (const float*)d_in[1];
    const float* ln1b   = (const float*)d_in[2];
    const float* Wqkv   = (const float*)d_in[3];
    const float* qscale = (const float*)d_in[4];
    const float* kscale = (const float*)d_in[5];
    const float* Wout   = (const float*)d_in[6];
    const float* ln2g   = (const float*)d_in[7];
    const float* ln2b   = (const float*)d_in[8];
    const float* W1     = (const float*)d_in[9];
    const float* b1     = (const float*)d_in[10];
    const float* W2     = (const float*)d_in[11];
    const float* b2     = (const float*)d_in[12];
    float* out = (float*)d_out;

    char* ws = (char*)d_ws;
    const size_t MB = 1024 * 1024;
    bf16* h   = (bf16*)(ws);             // 16 MB (reused: attn out o, then h2)
    bf16* qb  = (bf16*)(ws + 16 * MB);   // q/k/v contiguous 16..64 MB
    bf16* kb  = (bf16*)(ws + 32 * MB);
    bf16* vb  = (bf16*)(ws + 48 * MB);
    bf16* wts = (bf16*)(ws + 64 * MB);   // bf16 transposed weights, ~6.2 MB
    bf16* WqkvT = wts;                   // [1536][512]
    bf16* WoutT = WqkvT + 1536 * 512;    // [512][512]
    bf16* W1T   = WoutT + 512 * 512;     // [2816][512] (rows >=2730 zero)
    bf16* W2T   = W1T + 2816 * 512;      // [512][1408] (cols >=1365 zero)
    bf16* ob  = h;
    bf16* h2  = h;
    bf16* act = qb;                      // 46.2 MB over dead q/k/v
    float* x1 = out;                     // pre-FF residual lives in d_out

    // 0. merged prep: LN1 + all 4 weight transposes in one dispatch
    prep_kernel<<<4096 + 768 + 256 + 1408 + 704, 256, 0, stream>>>(
        x, ln1g, ln1b, h, Wqkv, WqkvT, Wout, WoutT, W1, W1T, W2, W2T);
    // 1. QKV GEMM with fused l2norm+scale+rotary epilogue -> per-head q/k/v
    gemm_bt<0><<<dim3(12, 128), 256, 0, stream>>>(h, WqkvT, 512, qb, nullptr,
                                                  qscale, kscale);
    // 2. local attention (128-row q-tiles, XCD-swizzled flat grid)
    attn_kernel<<<1024, 256, 0, stream>>>(qb, kb, vb, ob);
    // 3. out-proj + residual -> x1 (d_out, fp32)
    gemm_bt<1><<<dim3(4, 128), 256, 0, stream>>>(ob, WoutT, 512, nullptr, x1, x, nullptr);
    // 4. LN2 (reads d_out)
    ln_kernel<<<4096, 256, 0, stream>>>(x1, ln2g, ln2b, h2);
    // 5. FF1 fused dual-half + exact gelu -> act
    ff1_kernel<<<dim3(22, 128), 256, 0, stream>>>(h2, W1T, b1, act);
    // 6. FF2 + b2 + residual (in-place on d_out)
    gemm_bt<2><<<dim3(4, 128), 256, 0, stream>>>(act, W2T, 1408, nullptr, out, x1, b2);
}